// Round 8
// baseline (179.782 us; speedup 1.0000x reference)
//
#include <hip/hip_runtime.h>
#include <hip/hip_bf16.h>
#include <math.h>

#define N_SEQ 4096
#define M_DIM 1024
#define A_DIM 128
#define H_DIM 1152

typedef __attribute__((ext_vector_type(4))) float f32x4;
typedef __attribute__((ext_vector_type(8))) short bf16x8;
typedef __attribute__((ext_vector_type(4))) short bf16x4;

__device__ __forceinline__ unsigned short f2b(float f) {
  union { float f; unsigned int u; } v; v.f = f;
  unsigned int u = v.u;
  unsigned int r = (u + 0x7fffu + ((u >> 16) & 1u)) >> 16;
  return (unsigned short)r;
}
__device__ __forceinline__ float b2f(unsigned short u) {
  union { unsigned int i; float f; } v; v.i = ((unsigned int)u) << 16; return v.f;
}
__device__ __forceinline__ void gload_lds16(const void* g, void* l) {
  __builtin_amdgcn_global_load_lds((const __attribute__((address_space(1))) unsigned int*)g,
                                   (__attribute__((address_space(3))) unsigned int*)l,
                                   16, 0, 0);
}

// ---------------- fused convert (10 segs) + d_out zero-fill (seg 10), one launch ----
struct CvtArgs {
  const float* src[10];
  unsigned short* dst[10];
  float* zf;               // zero-fill base (d_out)
  unsigned int pfx[12];    // prefix in 4-elem groups; [10]=cvt end, [11]=total
};
__global__ __launch_bounds__(256) void k_f2b_multi(CvtArgs a) {
  unsigned int g = blockIdx.x * 256 + threadIdx.x;
  if (g >= a.pfx[10]) {
    *reinterpret_cast<float4*>(a.zf + (size_t)(g - a.pfx[10]) * 4) =
        make_float4(0.f, 0.f, 0.f, 0.f);
    return;
  }
  const float* sp = a.src[0];
  unsigned short* dp = a.dst[0];
  unsigned int base = 0;
#pragma unroll
  for (int i = 1; i < 10; i++)
    if (g >= a.pfx[i]) { sp = a.src[i]; dp = a.dst[i]; base = a.pfx[i]; }
  unsigned int i4 = g - base;
  float4 f = *reinterpret_cast<const float4*>(sp + (size_t)i4 * 4);
  ushort4 o;
  o.x = f2b(f.x); o.y = f2b(f.y); o.z = f2b(f.z); o.w = f2b(f.w);
  *reinterpret_cast<ushort4*>(dp + (size_t)i4 * 4) = o;
}

// ---------------- row LayerNorm (optional residual, f32/bf16 out) ----------------
__global__ __launch_bounds__(256) void k_ln(const float* __restrict__ src,
                                            const float* __restrict__ res,
                                            const float* __restrict__ g,
                                            const float* __restrict__ b,
                                            float* __restrict__ dstf,
                                            unsigned short* __restrict__ dstb,
                                            int D, int ostride, int ooff) {
  int i = blockIdx.x, tid = threadIdx.x, wave = tid >> 6, lane = tid & 63;
  __shared__ float rb[8];
  float v[4];
  int cnt = 0;
  float s = 0.f, ss = 0.f;
  for (int t = tid; t < D; t += 256) {
    float x = src[(size_t)i * D + t];
    if (res) x += res[(size_t)i * D + t];
    v[cnt++] = x; s += x; ss += x * x;
  }
  for (int o = 32; o; o >>= 1) { s += __shfl_xor(s, o); ss += __shfl_xor(ss, o); }
  if (!lane) { rb[wave] = s; rb[4 + wave] = ss; }
  __syncthreads();
  float S = rb[0] + rb[1] + rb[2] + rb[3];
  float SS = rb[4] + rb[5] + rb[6] + rb[7];
  float mu = S / (float)D;
  float var = SS / (float)D - mu * mu;
  float rstd = rsqrtf(var + 1e-6f);
  cnt = 0;
  for (int t = tid; t < D; t += 256) {
    float o = (v[cnt++] - mu) * rstd * g[t] + b[t];
    if (dstf) dstf[(size_t)i * D + t] = o;
    if (dstb) dstb[(size_t)i * ostride + ooff + t] = f2b(o);
  }
}

// ---------------- fused LN pair -> h_bf[4096][1152] ----------------
__device__ __forceinline__ void ln_body(const float* __restrict__ src,
                                        const float* __restrict__ res,
                                        const float* __restrict__ g,
                                        const float* __restrict__ b,
                                        unsigned short* __restrict__ dstb,
                                        int D, int ooff, int i, float* rb) {
  int tid = threadIdx.x, wave = tid >> 6, lane = tid & 63;
  float v[4];
  int cnt = 0;
  float s = 0.f, ss = 0.f;
  for (int t = tid; t < D; t += 256) {
    float x = src[(size_t)i * D + t] + res[(size_t)i * D + t];
    v[cnt++] = x; s += x; ss += x * x;
  }
  for (int o = 32; o; o >>= 1) { s += __shfl_xor(s, o); ss += __shfl_xor(ss, o); }
  if (!lane) { rb[wave] = s; rb[4 + wave] = ss; }
  __syncthreads();
  float S = rb[0] + rb[1] + rb[2] + rb[3];
  float SS = rb[4] + rb[5] + rb[6] + rb[7];
  float mu = S / (float)D;
  float var = SS / (float)D - mu * mu;
  float rstd = rsqrtf(var + 1e-6f);
  cnt = 0;
  for (int t = tid; t < D; t += 256) {
    float o = (v[cnt++] - mu) * rstd * g[t] + b[t];
    dstb[(size_t)i * H_DIM + ooff + t] = f2b(o);
  }
}
__global__ __launch_bounds__(256) void k_ln2(const float* __restrict__ s1,
                                             const float* __restrict__ r1,
                                             const float* __restrict__ g1,
                                             const float* __restrict__ b1,
                                             const float* __restrict__ s2,
                                             const float* __restrict__ r2,
                                             const float* __restrict__ g2,
                                             const float* __restrict__ b2,
                                             unsigned short* __restrict__ dstb) {
  __shared__ float rb[8];
  int bid = blockIdx.x;
  if (bid < N_SEQ) ln_body(s1, r1, g1, b1, dstb, 1024, 0, bid, rb);
  else             ln_body(s2, r2, g2, b2, dstb, 128, 1024, bid - N_SEQ, rb);
}

// ---------------- bf16 MFMA GEMM: 3-buffer counted-vmcnt pipeline (T3/T4) ----------
// C[M][N] = A[M][K]*B[N][K]^T; 128x128 tile, 4 waves, 4x4 frags of 16x16x32.
// Per step: STAGE(t+2) -> vmcnt(8) [leave t+1,t+2 in flight] -> barrier -> reads+MFMA
// -> barrier. No full drain in steady state; HBM latency gets ~2 steps of cover.
// LDS slot-rotation swizzle kept (bank conflicts = 0, verified R7).
struct GemmDesc {
  const unsigned short* A;
  const unsigned short* B;
  float* Cf;
  unsigned short* Cb;
  int K, N, gx, nb;
};
__global__ __launch_bounds__(256) void k_gemmx(GemmDesc d0, GemmDesc d1) {
  __shared__ __attribute__((aligned(16))) unsigned short As[3][128 * 32];
  __shared__ __attribute__((aligned(16))) unsigned short Bs[3][128 * 32];
  int tid = threadIdx.x;
  int bid = blockIdx.x;
  GemmDesc d = d0;
  int lid = bid;
  if (bid >= d0.nb) { d = d1; lid = bid - d0.nb; }
  // bijective XCD swizzle within segment
  int nwg = d.nb, q = nwg >> 3, r = nwg & 7;
  int xcd = lid & 7, idx = lid >> 3;
  int wgid = (xcd < r ? xcd * (q + 1) : r * (q + 1) + (xcd - r) * q) + idx;
  int bx = wgid % d.gx, by = wgid / d.gx;
  int row0 = by * 128, col0 = bx * 128;
  const int K = d.K, N = d.N;

  int wave = tid >> 6, lane = tid & 63;
  int wr = (wave >> 1) * 64, wc = (wave & 1) * 64;
  int lr = lane & 15;
  int lkb = ((((lane >> 4) + ((lr >> 1) & 3)) & 3)) * 16;
  int ch = wave * 2;
  int srow = ch * 16 + (lane >> 2);
  int scol = ((((lane & 3) - ((lane >> 3) & 3)) & 3)) * 8;
  const unsigned short* ga0 = d.A + (size_t)(row0 + srow) * K + scol;
  const unsigned short* ga1 = ga0 + (size_t)16 * K;
  const unsigned short* gb0 = d.B + (size_t)(col0 + srow) * K + scol;
  const unsigned short* gb1 = gb0 + (size_t)16 * K;

  f32x4 acc[4][4];
#pragma unroll
  for (int m = 0; m < 4; m++)
#pragma unroll
    for (int n = 0; n < 4; n++) acc[m][n] = (f32x4){0.f, 0.f, 0.f, 0.f};

  auto STAGE = [&](int buf, int t) {
    int k0 = t << 5;
    char* la = (char*)(&As[buf][0]) + ch * 1024;
    char* lb = (char*)(&Bs[buf][0]) + ch * 1024;
    gload_lds16(ga0 + k0, la);
    gload_lds16(ga1 + k0, la + 1024);
    gload_lds16(gb0 + k0, lb);
    gload_lds16(gb1 + k0, lb + 1024);
  };

  int nt = K >> 5;                 // >= 4 for all our shapes
  STAGE(0, 0);
  STAGE(1, 1);
  int cur = 0, sb = 2;             // sb = buffer for tile t+2
  for (int t = 0; t < nt; t++) {
    if (t + 2 < nt) {
      STAGE(sb, t + 2);
      asm volatile("s_waitcnt vmcnt(8)" ::: "memory");   // oldest 4 (tile t) landed
    } else if (t + 1 < nt) {
      asm volatile("s_waitcnt vmcnt(4)" ::: "memory");
    } else {
      asm volatile("s_waitcnt vmcnt(0)" ::: "memory");
    }
    __builtin_amdgcn_s_barrier();
    __builtin_amdgcn_sched_barrier(0);                    // pin reads below barrier
    const char* pa = (const char*)(&As[cur][0]) + (wr + lr) * 64 + lkb;
    const char* pb = (const char*)(&Bs[cur][0]) + (wc + lr) * 64 + lkb;
    bf16x8 af[4], bfr[4];
#pragma unroll
    for (int m = 0; m < 4; m++) af[m] = *(const bf16x8*)(pa + m * 1024);
#pragma unroll
    for (int n = 0; n < 4; n++) bfr[n] = *(const bf16x8*)(pb + n * 1024);
#pragma unroll
    for (int m = 0; m < 4; m++)
#pragma unroll
      for (int n = 0; n < 4; n++)
        acc[m][n] = __builtin_amdgcn_mfma_f32_16x16x32_bf16(af[m], bfr[n], acc[m][n], 0, 0, 0);
    __builtin_amdgcn_sched_barrier(0);                    // pin MFMA cluster above barrier
    __builtin_amdgcn_s_barrier();                         // readers done before buf reuse
    cur = (cur == 2) ? 0 : cur + 1;
    sb = (sb == 2) ? 0 : sb + 1;
  }
  int lq = lane >> 4;
#pragma unroll
  for (int m = 0; m < 4; m++)
#pragma unroll
    for (int n = 0; n < 4; n++)
#pragma unroll
      for (int j = 0; j < 4; j++) {
        int rr = row0 + wr + m * 16 + lq * 4 + j;
        int cc = col0 + wc + n * 16 + lr;
        if (d.Cf) d.Cf[(size_t)rr * N + cc] = acc[m][n][j];
        if (d.Cb) d.Cb[(size_t)rr * N + cc] = f2b(acc[m][n][j]);
      }
}

// ---------------- fused banded attention (video blocks 0-255, audio 256-383) --------
__global__ __launch_bounds__(256) void k_attn(const unsigned short* __restrict__ kqv,
                                              const unsigned short* __restrict__ akqv,
                                              float* __restrict__ att,
                                              float* __restrict__ P,
                                              float* __restrict__ Pa) {
  __shared__ __attribute__((aligned(16))) char smem[53504];
  int tid = threadIdx.x, wave = tid >> 6, lane = tid & 63;
  if (blockIdx.x < 256) {
    unsigned short(*Qs)[264] = (unsigned short(*)[264])smem;
    unsigned short(*Ks)[264] = (unsigned short(*)[264])(smem + 8448);
    float(*lg)[64] = (float(*)[64])(smem + 42240);
    int i0 = blockIdx.x * 16;
    int jlo = max(i0 - 19, 0);
    int jhi = min(i0 + 34, N_SEQ - 1);
    int nk = jhi - jlo + 1;                  // <= 54
    int lr = lane & 15, lke = (lane >> 4) * 8;
    f32x4 acc = (f32x4){0.f, 0.f, 0.f, 0.f};
    for (int kc = 0; kc < M_DIM; kc += 256) {
      __syncthreads();
#pragma unroll
      for (int it = 0; it < 2; it++) {
        int qq = tid + it * 256;
        int rr = qq >> 5, c = (qq & 31) * 8;
        *(bf16x8*)&Qs[rr][c] =
            *(const bf16x8*)&kqv[(size_t)(i0 + rr) * 3072 + 1024 + kc + c];
      }
#pragma unroll
      for (int it = 0; it < 8; it++) {
        int qq = tid + it * 256;
        int rr = qq >> 5, c = (qq & 31) * 8;
        bf16x8 v = {0, 0, 0, 0, 0, 0, 0, 0};
        if (rr < nk) v = *(const bf16x8*)&kqv[(size_t)(jlo + rr) * 3072 + kc + c];
        *(bf16x8*)&Ks[rr][c] = v;
      }
      __syncthreads();
#pragma unroll
      for (int kk = 0; kk < 8; kk++) {
        bf16x8 a = *(const bf16x8*)&Qs[lr][kk * 32 + lke];
        bf16x8 b = *(const bf16x8*)&Ks[wave * 16 + lr][kk * 32 + lke];
        acc = __builtin_amdgcn_mfma_f32_16x16x32_bf16(a, b, acc, 0, 0, 0);
      }
    }
#pragma unroll
    for (int j = 0; j < 4; j++)
      lg[(lane >> 4) * 4 + j][wave * 16 + (lane & 15)] = acc[j] * 0.06f;
    __syncthreads();
#pragma unroll
    for (int qq = 0; qq < 4; qq++) {
      int rr = wave + qq * 4;
      int i = i0 + rr;
      int c = lane;
      int dd = i - (jlo + c);
      bool valid = (c < nk) && (dd > -20) && (dd < 20);
      float v = valid ? lg[rr][c] : -1e30f;
      float mx = v;
      for (int o = 32; o; o >>= 1) mx = fmaxf(mx, __shfl_xor(mx, o));
      float e = valid ? __expf(v - mx) : 0.f;
      float su = e;
      for (int o = 32; o; o >>= 1) su += __shfl_xor(su, o);
      float p = e / su;
      if (valid) {
        att[(size_t)i * N_SEQ + jlo + c] = p;
        P[(size_t)i * 40 + (jlo + c) - max(i - 19, 0)] = p;
      }
    }
  } else {
    unsigned short(*Qs)[136] = (unsigned short(*)[136])smem;
    unsigned short(*Ks)[136] = (unsigned short(*)[136])(smem + 8704);
    float(*lg)[112] = (float(*)[112])(smem + 39168);
    int i0 = (blockIdx.x - 256) * 32;
    int jlo = max(i0 - 39, 0);
    int jhi = min(i0 + 70, N_SEQ - 1);
    int nk = jhi - jlo + 1;                   // <= 110
    int lr = lane & 15, lke = (lane >> 4) * 8;
#pragma unroll
    for (int it = 0; it < 2; it++) {
      int qq = tid + it * 256;
      int rr = qq >> 4, c = (qq & 15) * 8;
      *(bf16x8*)&Qs[rr][c] = *(const bf16x8*)&akqv[(size_t)(i0 + rr) * 384 + 128 + c];
    }
#pragma unroll
    for (int it = 0; it < 7; it++) {
      int qq = tid + it * 256;
      int rr = qq >> 4, c = (qq & 15) * 8;
      bf16x8 v = {0, 0, 0, 0, 0, 0, 0, 0};
      if (rr < nk) v = *(const bf16x8*)&akqv[(size_t)(jlo + rr) * 384 + c];
      *(bf16x8*)&Ks[rr][c] = v;
    }
    __syncthreads();
    for (int ff = wave; ff < 14; ff += 4) {
      int fr = ff / 7, fc = ff % 7;
      f32x4 acc = (f32x4){0.f, 0.f, 0.f, 0.f};
#pragma unroll
      for (int kk = 0; kk < 4; kk++) {
        bf16x8 a = *(const bf16x8*)&Qs[fr * 16 + lr][kk * 32 + lke];
        bf16x8 b = *(const bf16x8*)&Ks[fc * 16 + lr][kk * 32 + lke];
        acc = __builtin_amdgcn_mfma_f32_16x16x32_bf16(a, b, acc, 0, 0, 0);
      }
#pragma unroll
      for (int j = 0; j < 4; j++)
        lg[fr * 16 + (lane >> 4) * 4 + j][fc * 16 + (lane & 15)] = acc[j] * 0.06f;
    }
    __syncthreads();
#pragma unroll
    for (int qq = 0; qq < 8; qq++) {
      int rr = wave + qq * 4;
      int i = i0 + rr;
      int c0 = lane, c1 = lane + 64;
      int e0i = i - (jlo + c0), e1i = i - (jlo + c1);
      bool v0 = (c0 < nk) && (e0i > -40) && (e0i < 40);
      bool v1 = (c1 < nk) && (e1i > -40) && (e1i < 40);
      float l0 = v0 ? lg[rr][c0] : -1e30f;
      float l1 = v1 ? lg[rr][min(c1, 111)] : -1e30f;
      float mx = fmaxf(l0, l1);
      for (int o = 32; o; o >>= 1) mx = fmaxf(mx, __shfl_xor(mx, o));
      float e0 = v0 ? __expf(l0 - mx) : 0.f;
      float e1 = v1 ? __expf(l1 - mx) : 0.f;
      float su = e0 + e1;
      for (int o = 32; o; o >>= 1) su += __shfl_xor(su, o);
      float inv = 1.f / su;
      int base = max(i - 39, 0);
      if (v0) Pa[(size_t)i * 79 + (jlo + c0) - base] = e0 * inv;
      if (v1) Pa[(size_t)i * 79 + (jlo + c1) - base] = e1 * inv;
    }
  }
}

// ---------------- fused PV, XCD-chunked + LDS-staged P + pipelined loops -----------
__global__ __launch_bounds__(256) void k_pv(const float* __restrict__ P,
                                            const float* __restrict__ Pa,
                                            const unsigned short* __restrict__ kqv,
                                            const unsigned short* __restrict__ akqv,
                                            unsigned short* __restrict__ y0b,
                                            unsigned short* __restrict__ ay0b) {
  int bid = blockIdx.x, tid = threadIdx.x;
  if (bid < 2048) {
    // ---- audio: 2 rows/block ----
    __shared__ float pa_s[2][80];
    int xcd = bid & 7, idx = bid >> 3;
    int half = tid >> 7, d = tid & 127;
    int i = (xcd * 256 + idx) * 2 + half;
    int jlo = max(i - 39, 0), jhi = min(i + 39, N_SEQ - 1);
    int nj = jhi - jlo + 1;                  // <= 79
    if (d < nj)
      pa_s[half][d] = Pa[(size_t)(jlo + d) * 79 + (i - max(jlo + d - 39, 0))];
    __syncthreads();
    float acc = 0.f;
#pragma unroll 8
    for (int t = 0; t < 79; t++) {
      bool v = t < nj;
      int j = v ? (jlo + t) : jhi;
      float a = v ? pa_s[half][t] : 0.f;
      acc += a * b2f(akqv[(size_t)j * 384 + 256 + d]);
    }
    ay0b[(size_t)i * 128 + d] = f2b(acc);
  } else {
    // ---- video: 1 row/block, 4 dims/thread ----
    __shared__ float pv_s[40];
    int vb = bid - 2048;
    int xcd = vb & 7, idx = vb >> 3;
    int i = xcd * 512 + idx;
    int jlo = max(i - 19, 0), jhi = min(i + 19, N_SEQ - 1);
    int nj = jhi - jlo + 1;                  // <= 39
    if (tid < nj)
      pv_s[tid] = P[(size_t)(jlo + tid) * 40 + (i - max(jlo + tid - 19, 0))];
    __syncthreads();
    int d0 = tid * 4;
    float a0 = 0.f, a1 = 0.f, a2 = 0.f, a3 = 0.f;
#pragma unroll
    for (int t = 0; t < 39; t++) {
      bool v = t < nj;
      int j = v ? (jlo + t) : jhi;
      float a = v ? pv_s[t] : 0.f;
      bf16x4 vv = *(const bf16x4*)&kqv[(size_t)j * 3072 + 2048 + d0];
      a0 += a * b2f((unsigned short)vv[0]);
      a1 += a * b2f((unsigned short)vv[1]);
      a2 += a * b2f((unsigned short)vv[2]);
      a3 += a * b2f((unsigned short)vv[3]);
    }
    ushort4 o;
    o.x = f2b(a0); o.y = f2b(a1); o.z = f2b(a2); o.w = f2b(a3);
    *(ushort4*)&y0b[(size_t)i * 1024 + d0] = o;
  }
}

// ---------------- head: relu(h2+b) -> LN -> dot(kd_w) -> sigmoid ----------------
__global__ __launch_bounds__(256) void k_head(const float* __restrict__ h2,
                                              const float* __restrict__ kab,
                                              const float* __restrict__ g,
                                              const float* __restrict__ b,
                                              const float* __restrict__ kdw,
                                              const float* __restrict__ kdb,
                                              float* __restrict__ out) {
  int i = blockIdx.x, tid = threadIdx.x, wave = tid >> 6, lane = tid & 63;
  __shared__ float rb[12];
  float v[4], s = 0.f, ss = 0.f;
#pragma unroll
  for (int q = 0; q < 4; q++) {
    int t = tid + q * 256;
    float x = h2[(size_t)i * 1024 + t] + kab[t];
    x = fmaxf(x, 0.f);
    v[q] = x; s += x; ss += x * x;
  }
  for (int o = 32; o; o >>= 1) { s += __shfl_xor(s, o); ss += __shfl_xor(ss, o); }
  if (!lane) { rb[wave] = s; rb[4 + wave] = ss; }
  __syncthreads();
  float S = rb[0] + rb[1] + rb[2] + rb[3];
  float SS = rb[4] + rb[5] + rb[6] + rb[7];
  float mu = S * (1.f / 1024.f);
  float var = SS * (1.f / 1024.f) - mu * mu;
  float rstd = rsqrtf(var + 1e-6f);
  float dacc = 0.f;
#pragma unroll
  for (int q = 0; q < 4; q++) {
    int t = tid + q * 256;
    dacc += ((v[q] - mu) * rstd * g[t] + b[t]) * kdw[t];
  }
  for (int o = 32; o; o >>= 1) dacc += __shfl_xor(dacc, o);
  if (!lane) rb[8 + wave] = dacc;
  __syncthreads();
  if (tid == 0) out[i] = 1.f / (1.f + __expf(-(rb[8] + rb[9] + rb[10] + rb[11] + kdb[0])));
}

extern "C" void kernel_launch(void* const* d_in, const int* in_sizes, int n_in,
                              void* d_out, int out_size, void* d_ws, size_t ws_size,
                              hipStream_t stream) {
  const float* x      = (const float*)d_in[0];
  const float* audio  = (const float*)d_in[1];
  const float* Wk     = (const float*)d_in[2];
  const float* Wq     = (const float*)d_in[3];
  const float* Wv     = (const float*)d_in[4];
  const float* Wo     = (const float*)d_in[5];
  const float* aWk    = (const float*)d_in[6];
  const float* aWq    = (const float*)d_in[7];
  const float* aWv    = (const float*)d_in[8];
  const float* aWo    = (const float*)d_in[9];
  const float* ka_w   = (const float*)d_in[10];
  const float* ka_b   = (const float*)d_in[11];
  const float* kd_w   = (const float*)d_in[12];
  const float* kd_b   = (const float*)d_in[13];
  const float* ln_y_g = (const float*)d_in[14];
  const float* ln_y_b = (const float*)d_in[15];
  const float* ln_ka_g= (const float*)d_in[16];
  const float* ln_ka_b= (const float*)d_in[17];
  const float* ln_a_g = (const float*)d_in[18];
  const float* ln_a_b = (const float*)d_in[19];
  const float* ln_a2_g= (const float*)d_in[20];
  const float* ln_a2_b= (const float*)d_in[21];

  const size_t MB = 1024ull * 1024ull;
  if (ws_size < 106 * MB) return;

  char* w = (char*)d_ws;
  unsigned short* kqv_bf  = (unsigned short*)(w);            // [4096][3072] bf16  24MB
  unsigned short* akqv_bf = (unsigned short*)(w + 24 * MB);  // [4096][384]  bf16   3MB
  float* y1    = (float*)(w + 27 * MB);                      // [4096][1024]       16MB
  float* h2    = (float*)(w + 43 * MB);                      // [4096][1024]       16MB
  float* aud32 = (float*)(w + 59 * MB);                      // [4096][128]         2MB
  float* ay1   = (float*)(w + 61 * MB);                      // [4096][128]         2MB
  float* P     = (float*)(w + 63 * MB);                      // [4096][40]        640KB
  float* Pa    = (float*)(w + 64 * MB);                      // [4096][79]        1.3MB
  unsigned short* x_bf     = (unsigned short*)(w + 66 * MB); // 8MB
  unsigned short* wkqv_bf  = (unsigned short*)(w + 74 * MB); // 6MB
  unsigned short* wo_bf    = (unsigned short*)(w + 80 * MB); // 2MB
  unsigned short* kaw_bf   = (unsigned short*)(w + 82 * MB); // 2.25MB
  unsigned short* awkqv_bf = (unsigned short*)(w + 85 * MB); // 96KB
  unsigned short* awo_bf   = (unsigned short*)(w + 86 * MB); // 32KB
  unsigned short* aud_bf   = (unsigned short*)(w + 87 * MB); // 1MB
  unsigned short* y0_bf    = (unsigned short*)(w + 88 * MB); // 8MB
  unsigned short* ay0_bf   = (unsigned short*)(w + 96 * MB); // 1MB
  unsigned short* h_bf     = (unsigned short*)(w + 97 * MB); // 9MB

  float* out0 = (float*)d_out;
  float* att  = (float*)d_out + N_SEQ;

  // fused convert + d_out zero-fill (one launch)
  CvtArgs ca;
  const unsigned int MM4 = (M_DIM * M_DIM) / 4;
  const unsigned int AA4 = (A_DIM * A_DIM) / 4;
  ca.src[0] = x;    ca.dst[0] = x_bf;
  ca.src[1] = Wk;   ca.dst[1] = wkqv_bf;
  ca.src[2] = Wq;   ca.dst[2] = wkqv_bf + M_DIM * M_DIM;
  ca.src[3] = Wv;   ca.dst[3] = wkqv_bf + 2 * M_DIM * M_DIM;
  ca.src[4] = Wo;   ca.dst[4] = wo_bf;
  ca.src[5] = ka_w; ca.dst[5] = kaw_bf;
  ca.src[6] = aWk;  ca.dst[6] = awkqv_bf;
  ca.src[7] = aWq;  ca.dst[7] = awkqv_bf + A_DIM * A_DIM;
  ca.src[8] = aWv;  ca.dst[8] = awkqv_bf + 2 * A_DIM * A_DIM;
  ca.src[9] = aWo;  ca.dst[9] = awo_bf;
  ca.zf = (float*)d_out;
  unsigned int sz4[10] = { (N_SEQ * M_DIM) / 4, MM4, MM4, MM4, MM4,
                           (1024u * H_DIM) / 4, AA4, AA4, AA4, AA4 };
  ca.pfx[0] = 0;
  for (int i = 0; i < 10; i++) ca.pfx[i + 1] = ca.pfx[i] + sz4[i];
  ca.pfx[11] = ca.pfx[10] + (unsigned int)(out_size / 4);
  k_f2b_multi<<<(ca.pfx[11] + 255) / 256, 256, 0, stream>>>(ca);

  // audio input LN -> f32 (residual) + bf16 (GEMM input)
  k_ln<<<N_SEQ, 256, 0, stream>>>(audio, nullptr, ln_a2_g, ln_a2_b, aud32, aud_bf,
                                  A_DIM, A_DIM, 0);

  // KQV + aKQV GEMMs (one launch)
  GemmDesc dk { x_bf,   wkqv_bf,  nullptr, kqv_bf,  1024, 3072, 24, 768 };
  GemmDesc da { aud_bf, awkqv_bf, nullptr, akqv_bf, 128,  384,  3,  96  };
  k_gemmx<<<dk.nb + da.nb, 256, 0, stream>>>(dk, da);

  // fused banded attention + fused PV (audio-first, XCD-chunked)
  k_attn<<<384, 256, 0, stream>>>(kqv_bf, akqv_bf, att, P, Pa);
  k_pv<<<2048 + N_SEQ, 256, 0, stream>>>(P, Pa, kqv_bf, akqv_bf, y0_bf, ay0_bf);

  // Wo + aWo projections (one launch)
  GemmDesc dw { y0_bf,  wo_bf,  y1,  nullptr, 1024, 1024, 8, 256 };
  GemmDesc dv { ay0_bf, awo_bf, ay1, nullptr, 128,  128,  1, 32  };
  k_gemmx<<<dw.nb + dv.nb, 256, 0, stream>>>(dw, dv);

  // fused residual+LN pair -> h_bf [4096][1152]
  k_ln2<<<2 * N_SEQ, 256, 0, stream>>>(y1, x, ln_y_g, ln_y_b,
                                       ay1, aud32, ln_a_g, ln_a_b, h_bf);

  // MLP GEMM (K=1152)
  GemmDesc dm { h_bf, kaw_bf, h2, nullptr, 1152, 1024, 8, 256 };
  GemmDesc dz { nullptr, nullptr, nullptr, nullptr, 32, 128, 1, 0 };
  k_gemmx<<<dm.nb, 256, 0, stream>>>(dm, dz);

  // relu+bias -> LN -> dot -> sigmoid
  k_head<<<N_SEQ, 256, 0, stream>>>(h2, ka_b, ln_ka_g, ln_ka_b, kd_w, kd_b, out0);
}

// Round 9
// 167.881 us; speedup vs baseline: 1.0709x; 1.0709x over previous
//
#include <hip/hip_runtime.h>
#include <hip/hip_bf16.h>
#include <math.h>

#define N_SEQ 4096
#define M_DIM 1024
#define A_DIM 128
#define H_DIM 1152

typedef __attribute__((ext_vector_type(4))) float f32x4;
typedef __attribute__((ext_vector_type(8))) short bf16x8;
typedef __attribute__((ext_vector_type(4))) short bf16x4;

__device__ __forceinline__ unsigned short f2b(float f) {
  union { float f; unsigned int u; } v; v.f = f;
  unsigned int u = v.u;
  unsigned int r = (u + 0x7fffu + ((u >> 16) & 1u)) >> 16;
  return (unsigned short)r;
}
__device__ __forceinline__ float b2f(unsigned short u) {
  union { unsigned int i; float f; } v; v.i = ((unsigned int)u) << 16; return v.f;
}
__device__ __forceinline__ void gload_lds16(const void* g, void* l) {
  __builtin_amdgcn_global_load_lds((const __attribute__((address_space(1))) unsigned int*)g,
                                   (__attribute__((address_space(3))) unsigned int*)l,
                                   16, 0, 0);
}

// ------- launch 1: fused f32->bf16 convert (10 segs) + audio LayerNorm tail --------
struct CvtArgs {
  const float* src[10];
  unsigned short* dst[10];
  unsigned int pfx[11];     // prefix in 4-elem groups
  unsigned int nblk_cvt;    // blocks for convert part
  const float* audio;
  const float* lng;
  const float* lnb;
  unsigned short* aud_bf;
};
__global__ __launch_bounds__(256) void k_f2b_multi(CvtArgs a) {
  int tid = threadIdx.x;
  if (blockIdx.x >= a.nblk_cvt) {
    // audio LN: 2 rows/block, 128 threads per row
    __shared__ float rb[8];
    int ab = blockIdx.x - a.nblk_cvt;          // 0..2047
    int i = ab * 2 + (tid >> 7), d = tid & 127;
    float x = a.audio[(size_t)i * A_DIM + d];
    float s = x, ss = x * x;
    for (int o = 32; o; o >>= 1) { s += __shfl_xor(s, o); ss += __shfl_xor(ss, o); }
    int wave = tid >> 6, lane = tid & 63;
    if (!lane) { rb[wave] = s; rb[4 + wave] = ss; }
    __syncthreads();
    int w0 = (tid >> 7) * 2;
    float S = rb[w0] + rb[w0 + 1], SS = rb[4 + w0] + rb[4 + w0 + 1];
    float mu = S * (1.f / 128.f);
    float var = SS * (1.f / 128.f) - mu * mu;
    float rstd = rsqrtf(var + 1e-6f);
    a.aud_bf[(size_t)i * A_DIM + d] = f2b((x - mu) * rstd * a.lng[d] + a.lnb[d]);
    return;
  }
  unsigned int g = blockIdx.x * 256 + tid;
  const float* sp = a.src[0];
  unsigned short* dp = a.dst[0];
  unsigned int base = 0;
#pragma unroll
  for (int i = 1; i < 10; i++)
    if (g >= a.pfx[i]) { sp = a.src[i]; dp = a.dst[i]; base = a.pfx[i]; }
  unsigned int i4 = g - base;
  float4 f = *reinterpret_cast<const float4*>(sp + (size_t)i4 * 4);
  ushort4 o;
  o.x = f2b(f.x); o.y = f2b(f.y); o.z = f2b(f.z); o.w = f2b(f.w);
  *reinterpret_cast<ushort4*>(dp + (size_t)i4 * 4) = o;
}

// ---------------- bf16 MFMA GEMM: 3-buffer counted-vmcnt pipeline -------------------
// + optional zero-fill segment (blocks beyond the two GEMM segments stream zeros into
// zf — rides the GEMM's idle write BW; bank-conflict-free LDS swizzle verified R7).
struct GemmDesc {
  const unsigned short* A;
  const unsigned short* B;
  float* Cf;
  unsigned short* Cb;
  int K, N, gx, nb;
};
__global__ __launch_bounds__(256) void k_gemmx(GemmDesc d0, GemmDesc d1, float* zf) {
  __shared__ __attribute__((aligned(16))) unsigned short As[3][128 * 32];
  __shared__ __attribute__((aligned(16))) unsigned short Bs[3][128 * 32];
  int tid = threadIdx.x;
  int bid = blockIdx.x;
  int gemmb = d0.nb + d1.nb;
  if (bid >= gemmb) {
    // zero-fill segment: 65536 f32 (256KB) per block
    float4* p = (float4*)(zf + (size_t)(bid - gemmb) * 65536);
    float4 z = make_float4(0.f, 0.f, 0.f, 0.f);
#pragma unroll
    for (int k = 0; k < 64; k++) p[tid + k * 256] = z;
    return;
  }
  GemmDesc d = d0;
  int lid = bid;
  if (bid >= d0.nb) { d = d1; lid = bid - d0.nb; }
  // bijective XCD swizzle within segment
  int nwg = d.nb, q = nwg >> 3, r = nwg & 7;
  int xcd = lid & 7, idx = lid >> 3;
  int wgid = (xcd < r ? xcd * (q + 1) : r * (q + 1) + (xcd - r) * q) + idx;
  int bx = wgid % d.gx, by = wgid / d.gx;
  int row0 = by * 128, col0 = bx * 128;
  const int K = d.K, N = d.N;

  int wave = tid >> 6, lane = tid & 63;
  int wr = (wave >> 1) * 64, wc = (wave & 1) * 64;
  int lr = lane & 15;
  int lkb = ((((lane >> 4) + ((lr >> 1) & 3)) & 3)) * 16;
  int ch = wave * 2;
  int srow = ch * 16 + (lane >> 2);
  int scol = ((((lane & 3) - ((lane >> 3) & 3)) & 3)) * 8;
  const unsigned short* ga0 = d.A + (size_t)(row0 + srow) * K + scol;
  const unsigned short* ga1 = ga0 + (size_t)16 * K;
  const unsigned short* gb0 = d.B + (size_t)(col0 + srow) * K + scol;
  const unsigned short* gb1 = gb0 + (size_t)16 * K;

  f32x4 acc[4][4];
#pragma unroll
  for (int m = 0; m < 4; m++)
#pragma unroll
    for (int n = 0; n < 4; n++) acc[m][n] = (f32x4){0.f, 0.f, 0.f, 0.f};

  auto STAGE = [&](int buf, int t) {
    int k0 = t << 5;
    char* la = (char*)(&As[buf][0]) + ch * 1024;
    char* lb = (char*)(&Bs[buf][0]) + ch * 1024;
    gload_lds16(ga0 + k0, la);
    gload_lds16(ga1 + k0, la + 1024);
    gload_lds16(gb0 + k0, lb);
    gload_lds16(gb1 + k0, lb + 1024);
  };

  int nt = K >> 5;
  STAGE(0, 0);
  STAGE(1, 1);
  int cur = 0, sb = 2;
  for (int t = 0; t < nt; t++) {
    if (t + 2 < nt) {
      STAGE(sb, t + 2);
      asm volatile("s_waitcnt vmcnt(8)" ::: "memory");
    } else if (t + 1 < nt) {
      asm volatile("s_waitcnt vmcnt(4)" ::: "memory");
    } else {
      asm volatile("s_waitcnt vmcnt(0)" ::: "memory");
    }
    __builtin_amdgcn_s_barrier();
    __builtin_amdgcn_sched_barrier(0);
    const char* pa = (const char*)(&As[cur][0]) + (wr + lr) * 64 + lkb;
    const char* pb = (const char*)(&Bs[cur][0]) + (wc + lr) * 64 + lkb;
    bf16x8 af[4], bfr[4];
#pragma unroll
    for (int m = 0; m < 4; m++) af[m] = *(const bf16x8*)(pa + m * 1024);
#pragma unroll
    for (int n = 0; n < 4; n++) bfr[n] = *(const bf16x8*)(pb + n * 1024);
#pragma unroll
    for (int m = 0; m < 4; m++)
#pragma unroll
      for (int n = 0; n < 4; n++)
        acc[m][n] = __builtin_amdgcn_mfma_f32_16x16x32_bf16(af[m], bfr[n], acc[m][n], 0, 0, 0);
    __builtin_amdgcn_sched_barrier(0);
    __builtin_amdgcn_s_barrier();
    cur = (cur == 2) ? 0 : cur + 1;
    sb = (sb == 2) ? 0 : sb + 1;
  }
  int lq = lane >> 4;
#pragma unroll
  for (int m = 0; m < 4; m++)
#pragma unroll
    for (int n = 0; n < 4; n++)
#pragma unroll
      for (int j = 0; j < 4; j++) {
        int rr = row0 + wr + m * 16 + lq * 4 + j;
        int cc = col0 + wc + n * 16 + lr;
        if (d.Cf) d.Cf[(size_t)rr * N + cc] = acc[m][n][j];
        if (d.Cb) d.Cb[(size_t)rr * N + cc] = f2b(acc[m][n][j]);
      }
}

// ---------------- fused banded attention (video blocks 0-255, audio 256-383) --------
__global__ __launch_bounds__(256) void k_attn(const unsigned short* __restrict__ kqv,
                                              const unsigned short* __restrict__ akqv,
                                              float* __restrict__ att,
                                              float* __restrict__ P,
                                              float* __restrict__ Pa) {
  __shared__ __attribute__((aligned(16))) char smem[53504];
  int tid = threadIdx.x, wave = tid >> 6, lane = tid & 63;
  if (blockIdx.x < 256) {
    unsigned short(*Qs)[264] = (unsigned short(*)[264])smem;
    unsigned short(*Ks)[264] = (unsigned short(*)[264])(smem + 8448);
    float(*lg)[64] = (float(*)[64])(smem + 42240);
    int i0 = blockIdx.x * 16;
    int jlo = max(i0 - 19, 0);
    int jhi = min(i0 + 34, N_SEQ - 1);
    int nk = jhi - jlo + 1;                  // <= 54
    int lr = lane & 15, lke = (lane >> 4) * 8;
    f32x4 acc = (f32x4){0.f, 0.f, 0.f, 0.f};
    for (int kc = 0; kc < M_DIM; kc += 256) {
      __syncthreads();
#pragma unroll
      for (int it = 0; it < 2; it++) {
        int qq = tid + it * 256;
        int rr = qq >> 5, c = (qq & 31) * 8;
        *(bf16x8*)&Qs[rr][c] =
            *(const bf16x8*)&kqv[(size_t)(i0 + rr) * 3072 + 1024 + kc + c];
      }
#pragma unroll
      for (int it = 0; it < 8; it++) {
        int qq = tid + it * 256;
        int rr = qq >> 5, c = (qq & 31) * 8;
        bf16x8 v = {0, 0, 0, 0, 0, 0, 0, 0};
        if (rr < nk) v = *(const bf16x8*)&kqv[(size_t)(jlo + rr) * 3072 + kc + c];
        *(bf16x8*)&Ks[rr][c] = v;
      }
      __syncthreads();
#pragma unroll
      for (int kk = 0; kk < 8; kk++) {
        bf16x8 a = *(const bf16x8*)&Qs[lr][kk * 32 + lke];
        bf16x8 b = *(const bf16x8*)&Ks[wave * 16 + lr][kk * 32 + lke];
        acc = __builtin_amdgcn_mfma_f32_16x16x32_bf16(a, b, acc, 0, 0, 0);
      }
    }
#pragma unroll
    for (int j = 0; j < 4; j++)
      lg[(lane >> 4) * 4 + j][wave * 16 + (lane & 15)] = acc[j] * 0.06f;
    __syncthreads();
#pragma unroll
    for (int qq = 0; qq < 4; qq++) {
      int rr = wave + qq * 4;
      int i = i0 + rr;
      int c = lane;
      int dd = i - (jlo + c);
      bool valid = (c < nk) && (dd > -20) && (dd < 20);
      float v = valid ? lg[rr][c] : -1e30f;
      float mx = v;
      for (int o = 32; o; o >>= 1) mx = fmaxf(mx, __shfl_xor(mx, o));
      float e = valid ? __expf(v - mx) : 0.f;
      float su = e;
      for (int o = 32; o; o >>= 1) su += __shfl_xor(su, o);
      float p = e / su;
      if (valid) {
        att[(size_t)i * N_SEQ + jlo + c] = p;
        P[(size_t)i * 40 + (jlo + c) - max(i - 19, 0)] = p;
      }
    }
  } else {
    unsigned short(*Qs)[136] = (unsigned short(*)[136])smem;
    unsigned short(*Ks)[136] = (unsigned short(*)[136])(smem + 8704);
    float(*lg)[112] = (float(*)[112])(smem + 39168);
    int i0 = (blockIdx.x - 256) * 32;
    int jlo = max(i0 - 39, 0);
    int jhi = min(i0 + 70, N_SEQ - 1);
    int nk = jhi - jlo + 1;                   // <= 110
    int lr = lane & 15, lke = (lane >> 4) * 8;
#pragma unroll
    for (int it = 0; it < 2; it++) {
      int qq = tid + it * 256;
      int rr = qq >> 4, c = (qq & 15) * 8;
      *(bf16x8*)&Qs[rr][c] = *(const bf16x8*)&akqv[(size_t)(i0 + rr) * 384 + 128 + c];
    }
#pragma unroll
    for (int it = 0; it < 7; it++) {
      int qq = tid + it * 256;
      int rr = qq >> 4, c = (qq & 15) * 8;
      bf16x8 v = {0, 0, 0, 0, 0, 0, 0, 0};
      if (rr < nk) v = *(const bf16x8*)&akqv[(size_t)(jlo + rr) * 384 + c];
      *(bf16x8*)&Ks[rr][c] = v;
    }
    __syncthreads();
    for (int ff = wave; ff < 14; ff += 4) {
      int fr = ff / 7, fc = ff % 7;
      f32x4 acc = (f32x4){0.f, 0.f, 0.f, 0.f};
#pragma unroll
      for (int kk = 0; kk < 4; kk++) {
        bf16x8 a = *(const bf16x8*)&Qs[fr * 16 + lr][kk * 32 + lke];
        bf16x8 b = *(const bf16x8*)&Ks[fc * 16 + lr][kk * 32 + lke];
        acc = __builtin_amdgcn_mfma_f32_16x16x32_bf16(a, b, acc, 0, 0, 0);
      }
#pragma unroll
      for (int j = 0; j < 4; j++)
        lg[fr * 16 + (lane >> 4) * 4 + j][fc * 16 + (lane & 15)] = acc[j] * 0.06f;
    }
    __syncthreads();
#pragma unroll
    for (int qq = 0; qq < 8; qq++) {
      int rr = wave + qq * 4;
      int i = i0 + rr;
      int c0 = lane, c1 = lane + 64;
      int e0i = i - (jlo + c0), e1i = i - (jlo + c1);
      bool v0 = (c0 < nk) && (e0i > -40) && (e0i < 40);
      bool v1 = (c1 < nk) && (e1i > -40) && (e1i < 40);
      float l0 = v0 ? lg[rr][c0] : -1e30f;
      float l1 = v1 ? lg[rr][min(c1, 111)] : -1e30f;
      float mx = fmaxf(l0, l1);
      for (int o = 32; o; o >>= 1) mx = fmaxf(mx, __shfl_xor(mx, o));
      float e0 = v0 ? __expf(l0 - mx) : 0.f;
      float e1 = v1 ? __expf(l1 - mx) : 0.f;
      float su = e0 + e1;
      for (int o = 32; o; o >>= 1) su += __shfl_xor(su, o);
      float inv = 1.f / su;
      int base = max(i - 39, 0);
      if (v0) Pa[(size_t)i * 79 + (jlo + c0) - base] = e0 * inv;
      if (v1) Pa[(size_t)i * 79 + (jlo + c1) - base] = e1 * inv;
    }
  }
}

// ---------------- fused PV, XCD-chunked + LDS-staged P + pipelined loops -----------
__global__ __launch_bounds__(256) void k_pv(const float* __restrict__ P,
                                            const float* __restrict__ Pa,
                                            const unsigned short* __restrict__ kqv,
                                            const unsigned short* __restrict__ akqv,
                                            unsigned short* __restrict__ y0b,
                                            unsigned short* __restrict__ ay0b) {
  int bid = blockIdx.x, tid = threadIdx.x;
  if (bid < 2048) {
    __shared__ float pa_s[2][80];
    int xcd = bid & 7, idx = bid >> 3;
    int half = tid >> 7, d = tid & 127;
    int i = (xcd * 256 + idx) * 2 + half;
    int jlo = max(i - 39, 0), jhi = min(i + 39, N_SEQ - 1);
    int nj = jhi - jlo + 1;                  // <= 79
    if (d < nj)
      pa_s[half][d] = Pa[(size_t)(jlo + d) * 79 + (i - max(jlo + d - 39, 0))];
    __syncthreads();
    float acc = 0.f;
#pragma unroll 8
    for (int t = 0; t < 79; t++) {
      bool v = t < nj;
      int j = v ? (jlo + t) : jhi;
      float a = v ? pa_s[half][t] : 0.f;
      acc += a * b2f(akqv[(size_t)j * 384 + 256 + d]);
    }
    ay0b[(size_t)i * 128 + d] = f2b(acc);
  } else {
    __shared__ float pv_s[40];
    int vb = bid - 2048;
    int xcd = vb & 7, idx = vb >> 3;
    int i = xcd * 512 + idx;
    int jlo = max(i - 19, 0), jhi = min(i + 19, N_SEQ - 1);
    int nj = jhi - jlo + 1;                  // <= 39
    if (tid < nj)
      pv_s[tid] = P[(size_t)(jlo + tid) * 40 + (i - max(jlo + tid - 19, 0))];
    __syncthreads();
    int d0 = tid * 4;
    float a0 = 0.f, a1 = 0.f, a2 = 0.f, a3 = 0.f;
#pragma unroll
    for (int t = 0; t < 39; t++) {
      bool v = t < nj;
      int j = v ? (jlo + t) : jhi;
      float a = v ? pv_s[t] : 0.f;
      bf16x4 vv = *(const bf16x4*)&kqv[(size_t)j * 3072 + 2048 + d0];
      a0 += a * b2f((unsigned short)vv[0]);
      a1 += a * b2f((unsigned short)vv[1]);
      a2 += a * b2f((unsigned short)vv[2]);
      a3 += a * b2f((unsigned short)vv[3]);
    }
    ushort4 o;
    o.x = f2b(a0); o.y = f2b(a1); o.z = f2b(a2); o.w = f2b(a3);
    *(ushort4*)&y0b[(size_t)i * 1024 + d0] = o;
  }
}

// ---------------- fused residual+LN pair (bf16 in) -> h_bf[4096][1152] -------------
__global__ __launch_bounds__(256) void k_ln2(const unsigned short* __restrict__ s1,
                                             const unsigned short* __restrict__ r1,
                                             const float* __restrict__ g1,
                                             const float* __restrict__ b1,
                                             const unsigned short* __restrict__ s2,
                                             const unsigned short* __restrict__ r2,
                                             const float* __restrict__ g2,
                                             const float* __restrict__ b2,
                                             unsigned short* __restrict__ dstb) {
  __shared__ float rb[8];
  int bid = blockIdx.x, tid = threadIdx.x, wave = tid >> 6, lane = tid & 63;
  if (bid < N_SEQ) {
    int i = bid;
    bf16x4 sv = *(const bf16x4*)&s1[(size_t)i * 1024 + tid * 4];
    bf16x4 rv = *(const bf16x4*)&r1[(size_t)i * 1024 + tid * 4];
    float v[4], s = 0.f, ss = 0.f;
#pragma unroll
    for (int q = 0; q < 4; q++) {
      float xx = b2f((unsigned short)sv[q]) + b2f((unsigned short)rv[q]);
      v[q] = xx; s += xx; ss += xx * xx;
    }
    for (int o = 32; o; o >>= 1) { s += __shfl_xor(s, o); ss += __shfl_xor(ss, o); }
    if (!lane) { rb[wave] = s; rb[4 + wave] = ss; }
    __syncthreads();
    float S = rb[0] + rb[1] + rb[2] + rb[3];
    float SS = rb[4] + rb[5] + rb[6] + rb[7];
    float mu = S * (1.f / 1024.f);
    float var = SS * (1.f / 1024.f) - mu * mu;
    float rstd = rsqrtf(var + 1e-6f);
    float4 gv = *(const float4*)&g1[tid * 4];
    float4 bv = *(const float4*)&b1[tid * 4];
    ushort4 o;
    o.x = f2b((v[0] - mu) * rstd * gv.x + bv.x);
    o.y = f2b((v[1] - mu) * rstd * gv.y + bv.y);
    o.z = f2b((v[2] - mu) * rstd * gv.z + bv.z);
    o.w = f2b((v[3] - mu) * rstd * gv.w + bv.w);
    *(ushort4*)&dstb[(size_t)i * H_DIM + tid * 4] = o;
  } else {
    int i = bid - N_SEQ;
    float xx = 0.f;
    if (tid < 128) xx = b2f(s2[(size_t)i * 128 + tid]) + b2f(r2[(size_t)i * 128 + tid]);
    float s = xx, ss = xx * xx;
    for (int o = 32; o; o >>= 1) { s += __shfl_xor(s, o); ss += __shfl_xor(ss, o); }
    if (!lane) { rb[wave] = s; rb[4 + wave] = ss; }
    __syncthreads();
    float S = rb[0] + rb[1] + rb[2] + rb[3];
    float SS = rb[4] + rb[5] + rb[6] + rb[7];
    float mu = S * (1.f / 128.f);
    float var = SS * (1.f / 128.f) - mu * mu;
    float rstd = rsqrtf(var + 1e-6f);
    if (tid < 128)
      dstb[(size_t)i * H_DIM + 1024 + tid] = f2b((xx - mu) * rstd * g2[tid] + b2[tid]);
  }
}

// ---------------- head: relu(h2b+b) -> LN -> dot(kd_w) -> sigmoid (bf16 in) --------
__global__ __launch_bounds__(256) void k_head(const unsigned short* __restrict__ h2b,
                                              const float* __restrict__ kab,
                                              const float* __restrict__ g,
                                              const float* __restrict__ b,
                                              const float* __restrict__ kdw,
                                              const float* __restrict__ kdb,
                                              float* __restrict__ out) {
  int i = blockIdx.x, tid = threadIdx.x, wave = tid >> 6, lane = tid & 63;
  __shared__ float rb[12];
  bf16x4 hv = *(const bf16x4*)&h2b[(size_t)i * 1024 + tid * 4];
  float4 kb = *(const float4*)&kab[tid * 4];
  float v[4], s = 0.f, ss = 0.f;
  v[0] = fmaxf(b2f((unsigned short)hv[0]) + kb.x, 0.f);
  v[1] = fmaxf(b2f((unsigned short)hv[1]) + kb.y, 0.f);
  v[2] = fmaxf(b2f((unsigned short)hv[2]) + kb.z, 0.f);
  v[3] = fmaxf(b2f((unsigned short)hv[3]) + kb.w, 0.f);
#pragma unroll
  for (int q = 0; q < 4; q++) { s += v[q]; ss += v[q] * v[q]; }
  for (int o = 32; o; o >>= 1) { s += __shfl_xor(s, o); ss += __shfl_xor(ss, o); }
  if (!lane) { rb[wave] = s; rb[4 + wave] = ss; }
  __syncthreads();
  float S = rb[0] + rb[1] + rb[2] + rb[3];
  float SS = rb[4] + rb[5] + rb[6] + rb[7];
  float mu = S * (1.f / 1024.f);
  float var = SS * (1.f / 1024.f) - mu * mu;
  float rstd = rsqrtf(var + 1e-6f);
  float4 gv = *(const float4*)&g[tid * 4];
  float4 bv = *(const float4*)&b[tid * 4];
  float4 kv = *(const float4*)&kdw[tid * 4];
  float dacc = ((v[0] - mu) * rstd * gv.x + bv.x) * kv.x +
               ((v[1] - mu) * rstd * gv.y + bv.y) * kv.y +
               ((v[2] - mu) * rstd * gv.z + bv.z) * kv.z +
               ((v[3] - mu) * rstd * gv.w + bv.w) * kv.w;
  for (int o = 32; o; o >>= 1) dacc += __shfl_xor(dacc, o);
  if (!lane) rb[8 + wave] = dacc;
  __syncthreads();
  if (tid == 0) out[i] = 1.f / (1.f + __expf(-(rb[8] + rb[9] + rb[10] + rb[11] + kdb[0])));
}

extern "C" void kernel_launch(void* const* d_in, const int* in_sizes, int n_in,
                              void* d_out, int out_size, void* d_ws, size_t ws_size,
                              hipStream_t stream) {
  const float* x      = (const float*)d_in[0];
  const float* audio  = (const float*)d_in[1];
  const float* Wk     = (const float*)d_in[2];
  const float* Wq     = (const float*)d_in[3];
  const float* Wv     = (const float*)d_in[4];
  const float* Wo     = (const float*)d_in[5];
  const float* aWk    = (const float*)d_in[6];
  const float* aWq    = (const float*)d_in[7];
  const float* aWv    = (const float*)d_in[8];
  const float* aWo    = (const float*)d_in[9];
  const float* ka_w   = (const float*)d_in[10];
  const float* ka_b   = (const float*)d_in[11];
  const float* kd_w   = (const float*)d_in[12];
  const float* kd_b   = (const float*)d_in[13];
  const float* ln_y_g = (const float*)d_in[14];
  const float* ln_y_b = (const float*)d_in[15];
  const float* ln_ka_g= (const float*)d_in[16];
  const float* ln_ka_b= (const float*)d_in[17];
  const float* ln_a_g = (const float*)d_in[18];
  const float* ln_a_b = (const float*)d_in[19];
  const float* ln_a2_g= (const float*)d_in[20];
  const float* ln_a2_b= (const float*)d_in[21];

  const size_t MB = 1024ull * 1024ull;
  if (ws_size < 90 * MB) return;

  char* w = (char*)d_ws;
  unsigned short* kqv_bf  = (unsigned short*)(w);            // [4096][3072] bf16  24MB
  unsigned short* akqv_bf = (unsigned short*)(w + 24 * MB);  // [4096][384]  bf16   3MB
  unsigned short* y1b     = (unsigned short*)(w + 27 * MB);  // [4096][1024] bf16   8MB
  unsigned short* h2b     = (unsigned short*)(w + 35 * MB);  // [4096][1024] bf16   8MB
  unsigned short* ay1b    = (unsigned short*)(w + 43 * MB);  // [4096][128]  bf16   1MB
  float* P     = (float*)(w + 44 * MB);                      // [4096][40]        640KB
  float* Pa    = (float*)(w + 45 * MB);                      // [4096][79]        1.3MB
  unsigned short* x_bf     = (unsigned short*)(w + 47 * MB); // 8MB
  unsigned short* wkqv_bf  = (unsigned short*)(w + 55 * MB); // 6MB
  unsigned short* wo_bf    = (unsigned short*)(w + 61 * MB); // 2MB
  unsigned short* kaw_bf   = (unsigned short*)(w + 63 * MB); // 2.25MB
  unsigned short* awkqv_bf = (unsigned short*)(w + 66 * MB); // 96KB
  unsigned short* awo_bf   = (unsigned short*)(w + 67 * MB); // 32KB
  unsigned short* aud_bf   = (unsigned short*)(w + 68 * MB); // 1MB
  unsigned short* y0_bf    = (unsigned short*)(w + 69 * MB); // 8MB
  unsigned short* ay0_bf   = (unsigned short*)(w + 77 * MB); // 1MB
  unsigned short* h_bf     = (unsigned short*)(w + 78 * MB); // 9MB

  float* out0 = (float*)d_out;
  float* att  = (float*)d_out + N_SEQ;

  // launch 1: convert + audio LN (no zero-fill here anymore)
  CvtArgs ca;
  const unsigned int MM4 = (M_DIM * M_DIM) / 4;
  const unsigned int AA4 = (A_DIM * A_DIM) / 4;
  ca.src[0] = x;    ca.dst[0] = x_bf;
  ca.src[1] = Wk;   ca.dst[1] = wkqv_bf;
  ca.src[2] = Wq;   ca.dst[2] = wkqv_bf + M_DIM * M_DIM;
  ca.src[3] = Wv;   ca.dst[3] = wkqv_bf + 2 * M_DIM * M_DIM;
  ca.src[4] = Wo;   ca.dst[4] = wo_bf;
  ca.src[5] = ka_w; ca.dst[5] = kaw_bf;
  ca.src[6] = aWk;  ca.dst[6] = awkqv_bf;
  ca.src[7] = aWq;  ca.dst[7] = awkqv_bf + A_DIM * A_DIM;
  ca.src[8] = aWv;  ca.dst[8] = awkqv_bf + 2 * A_DIM * A_DIM;
  ca.src[9] = aWo;  ca.dst[9] = awo_bf;
  unsigned int sz4[10] = { (N_SEQ * M_DIM) / 4, MM4, MM4, MM4, MM4,
                           (1024u * H_DIM) / 4, AA4, AA4, AA4, AA4 };
  ca.pfx[0] = 0;
  for (int i = 0; i < 10; i++) ca.pfx[i + 1] = ca.pfx[i] + sz4[i];
  ca.nblk_cvt = ca.pfx[10] / 256;
  ca.audio = audio; ca.lng = ln_a2_g; ca.lnb = ln_a2_b; ca.aud_bf = aud_bf;
  k_f2b_multi<<<ca.nblk_cvt + 2048, 256, 0, stream>>>(ca);

  // KQV + aKQV GEMMs + att zero-fill (256 extra store-blocks, ride idle write BW)
  GemmDesc dk { x_bf,   wkqv_bf,  nullptr, kqv_bf,  1024, 3072, 24, 768 };
  GemmDesc da { aud_bf, awkqv_bf, nullptr, akqv_bf, 128,  384,  3,  96  };
  k_gemmx<<<dk.nb + da.nb + 256, 256, 0, stream>>>(dk, da, att);

  // fused banded attention + fused PV (audio-first, XCD-chunked)
  k_attn<<<384, 256, 0, stream>>>(kqv_bf, akqv_bf, att, P, Pa);
  k_pv<<<2048 + N_SEQ, 256, 0, stream>>>(P, Pa, kqv_bf, akqv_bf, y0_bf, ay0_bf);

  // Wo + aWo projections -> bf16
  GemmDesc dw { y0_bf,  wo_bf,  nullptr, y1b,  1024, 1024, 8, 256 };
  GemmDesc dv { ay0_bf, awo_bf, nullptr, ay1b, 128,  128,  1, 32  };
  k_gemmx<<<dw.nb + dv.nb, 256, 0, stream>>>(dw, dv, nullptr);

  // fused residual+LN pair (bf16 in) -> h_bf [4096][1152]
  k_ln2<<<2 * N_SEQ, 256, 0, stream>>>(y1b, x_bf, ln_y_g, ln_y_b,
                                       ay1b, aud_bf, ln_a_g, ln_a_b, h_bf);

  // MLP GEMM (K=1152) -> bf16
  GemmDesc dm { h_bf, kaw_bf, nullptr, h2b, 1152, 1024, 8, 256 };
  GemmDesc dz { nullptr, nullptr, nullptr, nullptr, 32, 128, 1, 0 };
  k_gemmx<<<dm.nb, 256, 0, stream>>>(dm, dz, nullptr);

  // relu+bias -> LN -> dot -> sigmoid
  k_head<<<N_SEQ, 256, 0, stream>>>(h2b, ka_b, ln_ka_g, ln_ka_b, kd_w, kd_b, out0);
}

// Round 10
// 160.468 us; speedup vs baseline: 1.1204x; 1.0462x over previous
//
#include <hip/hip_runtime.h>
#include <hip/hip_bf16.h>
#include <math.h>

#define N_SEQ 4096
#define M_DIM 1024
#define A_DIM 128
#define H_DIM 1152

typedef __attribute__((ext_vector_type(4))) float f32x4;
typedef __attribute__((ext_vector_type(8))) short bf16x8;
typedef __attribute__((ext_vector_type(4))) short bf16x4;

__device__ __forceinline__ unsigned short f2b(float f) {
  union { float f; unsigned int u; } v; v.f = f;
  unsigned int u = v.u;
  unsigned int r = (u + 0x7fffu + ((u >> 16) & 1u)) >> 16;
  return (unsigned short)r;
}
__device__ __forceinline__ float b2f(unsigned short u) {
  union { unsigned int i; float f; } v; v.i = ((unsigned int)u) << 16; return v.f;
}
__device__ __forceinline__ void gload_lds16(const void* g, void* l) {
  __builtin_amdgcn_global_load_lds((const __attribute__((address_space(1))) unsigned int*)g,
                                   (__attribute__((address_space(3))) unsigned int*)l,
                                   16, 0, 0);
}

// ------- launch 1: fused f32->bf16 convert (10 segs) + audio LayerNorm tail --------
struct CvtArgs {
  const float* src[10];
  unsigned short* dst[10];
  unsigned int pfx[11];
  unsigned int nblk_cvt;
  const float* audio;
  const float* lng;
  const float* lnb;
  unsigned short* aud_bf;
};
__global__ __launch_bounds__(256) void k_f2b_multi(CvtArgs a) {
  int tid = threadIdx.x;
  if (blockIdx.x >= a.nblk_cvt) {
    __shared__ float rb[8];
    int ab = blockIdx.x - a.nblk_cvt;
    int i = ab * 2 + (tid >> 7), d = tid & 127;
    float x = a.audio[(size_t)i * A_DIM + d];
    float s = x, ss = x * x;
    for (int o = 32; o; o >>= 1) { s += __shfl_xor(s, o); ss += __shfl_xor(ss, o); }
    int wave = tid >> 6, lane = tid & 63;
    if (!lane) { rb[wave] = s; rb[4 + wave] = ss; }
    __syncthreads();
    int w0 = (tid >> 7) * 2;
    float S = rb[w0] + rb[w0 + 1], SS = rb[4 + w0] + rb[4 + w0 + 1];
    float mu = S * (1.f / 128.f);
    float var = SS * (1.f / 128.f) - mu * mu;
    float rstd = rsqrtf(var + 1e-6f);
    a.aud_bf[(size_t)i * A_DIM + d] = f2b((x - mu) * rstd * a.lng[d] + a.lnb[d]);
    return;
  }
  unsigned int g = blockIdx.x * 256 + tid;
  const float* sp = a.src[0];
  unsigned short* dp = a.dst[0];
  unsigned int base = 0;
#pragma unroll
  for (int i = 1; i < 10; i++)
    if (g >= a.pfx[i]) { sp = a.src[i]; dp = a.dst[i]; base = a.pfx[i]; }
  unsigned int i4 = g - base;
  float4 f = *reinterpret_cast<const float4*>(sp + (size_t)i4 * 4);
  ushort4 o;
  o.x = f2b(f.x); o.y = f2b(f.y); o.z = f2b(f.z); o.w = f2b(f.w);
  *reinterpret_cast<ushort4*>(dp + (size_t)i4 * 4) = o;
}

// ---------------- bf16 MFMA GEMM: 128x128 tile, 3-buffer counted-vmcnt -------------
struct GemmDesc {
  const unsigned short* A;
  const unsigned short* B;
  float* Cf;
  unsigned short* Cb;
  int K, N, gx, nb;
};
__global__ __launch_bounds__(256) void k_gemmx(GemmDesc d0, GemmDesc d1, float* zf) {
  __shared__ __attribute__((aligned(16))) unsigned short As[3][128 * 32];
  __shared__ __attribute__((aligned(16))) unsigned short Bs[3][128 * 32];
  int tid = threadIdx.x;
  int bid = blockIdx.x;
  int gemmb = d0.nb + d1.nb;
  if (bid >= gemmb) {
    float4* p = (float4*)(zf + (size_t)(bid - gemmb) * 65536);
    float4 z = make_float4(0.f, 0.f, 0.f, 0.f);
#pragma unroll
    for (int k = 0; k < 64; k++) p[tid + k * 256] = z;
    return;
  }
  GemmDesc d = d0;
  int lid = bid;
  if (bid >= d0.nb) { d = d1; lid = bid - d0.nb; }
  int nwg = d.nb, q = nwg >> 3, r = nwg & 7;
  int xcd = lid & 7, idx = lid >> 3;
  int wgid = (xcd < r ? xcd * (q + 1) : r * (q + 1) + (xcd - r) * q) + idx;
  int bx = wgid % d.gx, by = wgid / d.gx;
  int row0 = by * 128, col0 = bx * 128;
  const int K = d.K, N = d.N;

  int wave = tid >> 6, lane = tid & 63;
  int wr = (wave >> 1) * 64, wc = (wave & 1) * 64;
  int lr = lane & 15;
  int lkb = ((((lane >> 4) + ((lr >> 1) & 3)) & 3)) * 16;
  int ch = wave * 2;
  int srow = ch * 16 + (lane >> 2);
  int scol = ((((lane & 3) - ((lane >> 3) & 3)) & 3)) * 8;
  const unsigned short* ga0 = d.A + (size_t)(row0 + srow) * K + scol;
  const unsigned short* ga1 = ga0 + (size_t)16 * K;
  const unsigned short* gb0 = d.B + (size_t)(col0 + srow) * K + scol;
  const unsigned short* gb1 = gb0 + (size_t)16 * K;

  f32x4 acc[4][4];
#pragma unroll
  for (int m = 0; m < 4; m++)
#pragma unroll
    for (int n = 0; n < 4; n++) acc[m][n] = (f32x4){0.f, 0.f, 0.f, 0.f};

  auto STAGE = [&](int buf, int t) {
    int k0 = t << 5;
    char* la = (char*)(&As[buf][0]) + ch * 1024;
    char* lb = (char*)(&Bs[buf][0]) + ch * 1024;
    gload_lds16(ga0 + k0, la);
    gload_lds16(ga1 + k0, la + 1024);
    gload_lds16(gb0 + k0, lb);
    gload_lds16(gb1 + k0, lb + 1024);
  };

  int nt = K >> 5;
  STAGE(0, 0);
  STAGE(1, 1);
  int cur = 0, sb = 2;
  for (int t = 0; t < nt; t++) {
    if (t + 2 < nt) {
      STAGE(sb, t + 2);
      asm volatile("s_waitcnt vmcnt(8)" ::: "memory");
    } else if (t + 1 < nt) {
      asm volatile("s_waitcnt vmcnt(4)" ::: "memory");
    } else {
      asm volatile("s_waitcnt vmcnt(0)" ::: "memory");
    }
    __builtin_amdgcn_s_barrier();
    __builtin_amdgcn_sched_barrier(0);
    const char* pa = (const char*)(&As[cur][0]) + (wr + lr) * 64 + lkb;
    const char* pb = (const char*)(&Bs[cur][0]) + (wc + lr) * 64 + lkb;
    bf16x8 af[4], bfr[4];
#pragma unroll
    for (int m = 0; m < 4; m++) af[m] = *(const bf16x8*)(pa + m * 1024);
#pragma unroll
    for (int n = 0; n < 4; n++) bfr[n] = *(const bf16x8*)(pb + n * 1024);
#pragma unroll
    for (int m = 0; m < 4; m++)
#pragma unroll
      for (int n = 0; n < 4; n++)
        acc[m][n] = __builtin_amdgcn_mfma_f32_16x16x32_bf16(af[m], bfr[n], acc[m][n], 0, 0, 0);
    __builtin_amdgcn_sched_barrier(0);
    __builtin_amdgcn_s_barrier();
    cur = (cur == 2) ? 0 : cur + 1;
    sb = (sb == 2) ? 0 : sb + 1;
  }
  int lq = lane >> 4;
#pragma unroll
  for (int m = 0; m < 4; m++)
#pragma unroll
    for (int n = 0; n < 4; n++)
#pragma unroll
      for (int j = 0; j < 4; j++) {
        int rr = row0 + wr + m * 16 + lq * 4 + j;
        int cc = col0 + wc + n * 16 + lr;
        if (d.Cf) d.Cf[(size_t)rr * N + cc] = acc[m][n][j];
        if (d.Cb) d.Cb[(size_t)rr * N + cc] = f2b(acc[m][n][j]);
      }
}

// ---------------- bf16 MFMA GEMM: 128x64 tile (2 blocks/CU TLP variant) ------------
// 4 waves of 64x32; per-stage 3 loads (2 A + 1 B) -> vmcnt 6/3/0; same swizzle.
__global__ __launch_bounds__(256) void k_gemm64(GemmDesc d0, GemmDesc d1) {
  __shared__ __attribute__((aligned(16))) unsigned short As[3][128 * 32];
  __shared__ __attribute__((aligned(16))) unsigned short Bs[3][64 * 32];
  int tid = threadIdx.x;
  int bid = blockIdx.x;
  GemmDesc d = d0;
  int lid = bid;
  if (bid >= d0.nb) { d = d1; lid = bid - d0.nb; }
  int nwg = d.nb, q = nwg >> 3, r = nwg & 7;
  int xcd = lid & 7, idx = lid >> 3;
  int wgid = (xcd < r ? xcd * (q + 1) : r * (q + 1) + (xcd - r) * q) + idx;
  int bx = wgid % d.gx, by = wgid / d.gx;
  int row0 = by * 128, col0 = bx * 64;
  const int K = d.K, N = d.N;

  int wave = tid >> 6, lane = tid & 63;
  int wr = (wave >> 1) * 64, wc = (wave & 1) * 32;
  int lr = lane & 15;
  int lkb = ((((lane >> 4) + ((lr >> 1) & 3)) & 3)) * 16;
  int ch = wave * 2;
  int srow = ch * 16 + (lane >> 2);          // A rows staged by this lane (2 chunks)
  int srB  = wave * 16 + (lane >> 2);        // B row staged by this lane (1 chunk)
  int scol = ((((lane & 3) - ((lane >> 3) & 3)) & 3)) * 8;
  const unsigned short* ga0 = d.A + (size_t)(row0 + srow) * K + scol;
  const unsigned short* ga1 = ga0 + (size_t)16 * K;
  const unsigned short* gb0 = d.B + (size_t)(col0 + srB) * K + scol;

  f32x4 acc[4][2];
#pragma unroll
  for (int m = 0; m < 4; m++)
#pragma unroll
    for (int n = 0; n < 2; n++) acc[m][n] = (f32x4){0.f, 0.f, 0.f, 0.f};

  auto STAGE = [&](int buf, int t) {
    int k0 = t << 5;
    char* la = (char*)(&As[buf][0]) + ch * 1024;
    char* lb = (char*)(&Bs[buf][0]) + wave * 1024;
    gload_lds16(ga0 + k0, la);
    gload_lds16(ga1 + k0, la + 1024);
    gload_lds16(gb0 + k0, lb);
  };

  int nt = K >> 5;
  STAGE(0, 0);
  STAGE(1, 1);
  int cur = 0, sb = 2;
  for (int t = 0; t < nt; t++) {
    if (t + 2 < nt) {
      STAGE(sb, t + 2);
      asm volatile("s_waitcnt vmcnt(6)" ::: "memory");
    } else if (t + 1 < nt) {
      asm volatile("s_waitcnt vmcnt(3)" ::: "memory");
    } else {
      asm volatile("s_waitcnt vmcnt(0)" ::: "memory");
    }
    __builtin_amdgcn_s_barrier();
    __builtin_amdgcn_sched_barrier(0);
    const char* pa = (const char*)(&As[cur][0]) + (wr + lr) * 64 + lkb;
    const char* pb = (const char*)(&Bs[cur][0]) + (wc + lr) * 64 + lkb;
    bf16x8 af[4], bfr[2];
#pragma unroll
    for (int m = 0; m < 4; m++) af[m] = *(const bf16x8*)(pa + m * 1024);
#pragma unroll
    for (int n = 0; n < 2; n++) bfr[n] = *(const bf16x8*)(pb + n * 1024);
#pragma unroll
    for (int m = 0; m < 4; m++)
#pragma unroll
      for (int n = 0; n < 2; n++)
        acc[m][n] = __builtin_amdgcn_mfma_f32_16x16x32_bf16(af[m], bfr[n], acc[m][n], 0, 0, 0);
    __builtin_amdgcn_sched_barrier(0);
    __builtin_amdgcn_s_barrier();
    cur = (cur == 2) ? 0 : cur + 1;
    sb = (sb == 2) ? 0 : sb + 1;
  }
  int lq = lane >> 4;
#pragma unroll
  for (int m = 0; m < 4; m++)
#pragma unroll
    for (int n = 0; n < 2; n++)
#pragma unroll
      for (int j = 0; j < 4; j++) {
        int rr = row0 + wr + m * 16 + lq * 4 + j;
        int cc = col0 + wc + n * 16 + lr;
        if (d.Cf) d.Cf[(size_t)rr * N + cc] = acc[m][n][j];
        if (d.Cb) d.Cb[(size_t)rr * N + cc] = f2b(acc[m][n][j]);
      }
}

// ---------------- fused banded attention (video blocks 0-255, audio 256-383) --------
__global__ __launch_bounds__(256) void k_attn(const unsigned short* __restrict__ kqv,
                                              const unsigned short* __restrict__ akqv,
                                              float* __restrict__ att,
                                              float* __restrict__ P,
                                              float* __restrict__ Pa) {
  __shared__ __attribute__((aligned(16))) char smem[53504];
  int tid = threadIdx.x, wave = tid >> 6, lane = tid & 63;
  if (blockIdx.x < 256) {
    unsigned short(*Qs)[264] = (unsigned short(*)[264])smem;
    unsigned short(*Ks)[264] = (unsigned short(*)[264])(smem + 8448);
    float(*lg)[64] = (float(*)[64])(smem + 42240);
    int i0 = blockIdx.x * 16;
    int jlo = max(i0 - 19, 0);
    int jhi = min(i0 + 34, N_SEQ - 1);
    int nk = jhi - jlo + 1;                  // <= 54
    int lr = lane & 15, lke = (lane >> 4) * 8;
    f32x4 acc = (f32x4){0.f, 0.f, 0.f, 0.f};
    for (int kc = 0; kc < M_DIM; kc += 256) {
      __syncthreads();
#pragma unroll
      for (int it = 0; it < 2; it++) {
        int qq = tid + it * 256;
        int rr = qq >> 5, c = (qq & 31) * 8;
        *(bf16x8*)&Qs[rr][c] =
            *(const bf16x8*)&kqv[(size_t)(i0 + rr) * 3072 + 1024 + kc + c];
      }
#pragma unroll
      for (int it = 0; it < 8; it++) {
        int qq = tid + it * 256;
        int rr = qq >> 5, c = (qq & 31) * 8;
        bf16x8 v = {0, 0, 0, 0, 0, 0, 0, 0};
        if (rr < nk) v = *(const bf16x8*)&kqv[(size_t)(jlo + rr) * 3072 + kc + c];
        *(bf16x8*)&Ks[rr][c] = v;
      }
      __syncthreads();
#pragma unroll
      for (int kk = 0; kk < 8; kk++) {
        bf16x8 a = *(const bf16x8*)&Qs[lr][kk * 32 + lke];
        bf16x8 b = *(const bf16x8*)&Ks[wave * 16 + lr][kk * 32 + lke];
        acc = __builtin_amdgcn_mfma_f32_16x16x32_bf16(a, b, acc, 0, 0, 0);
      }
    }
#pragma unroll
    for (int j = 0; j < 4; j++)
      lg[(lane >> 4) * 4 + j][wave * 16 + (lane & 15)] = acc[j] * 0.06f;
    __syncthreads();
#pragma unroll
    for (int qq = 0; qq < 4; qq++) {
      int rr = wave + qq * 4;
      int i = i0 + rr;
      int c = lane;
      int dd = i - (jlo + c);
      bool valid = (c < nk) && (dd > -20) && (dd < 20);
      float v = valid ? lg[rr][c] : -1e30f;
      float mx = v;
      for (int o = 32; o; o >>= 1) mx = fmaxf(mx, __shfl_xor(mx, o));
      float e = valid ? __expf(v - mx) : 0.f;
      float su = e;
      for (int o = 32; o; o >>= 1) su += __shfl_xor(su, o);
      float p = e / su;
      if (valid) {
        att[(size_t)i * N_SEQ + jlo + c] = p;
        P[(size_t)i * 40 + (jlo + c) - max(i - 19, 0)] = p;
      }
    }
  } else {
    unsigned short(*Qs)[136] = (unsigned short(*)[136])smem;
    unsigned short(*Ks)[136] = (unsigned short(*)[136])(smem + 8704);
    float(*lg)[112] = (float(*)[112])(smem + 39168);
    int i0 = (blockIdx.x - 256) * 32;
    int jlo = max(i0 - 39, 0);
    int jhi = min(i0 + 70, N_SEQ - 1);
    int nk = jhi - jlo + 1;                   // <= 110
    int lr = lane & 15, lke = (lane >> 4) * 8;
#pragma unroll
    for (int it = 0; it < 2; it++) {
      int qq = tid + it * 256;
      int rr = qq >> 4, c = (qq & 15) * 8;
      *(bf16x8*)&Qs[rr][c] = *(const bf16x8*)&akqv[(size_t)(i0 + rr) * 384 + 128 + c];
    }
#pragma unroll
    for (int it = 0; it < 7; it++) {
      int qq = tid + it * 256;
      int rr = qq >> 4, c = (qq & 15) * 8;
      bf16x8 v = {0, 0, 0, 0, 0, 0, 0, 0};
      if (rr < nk) v = *(const bf16x8*)&akqv[(size_t)(jlo + rr) * 384 + c];
      *(bf16x8*)&Ks[rr][c] = v;
    }
    __syncthreads();
    for (int ff = wave; ff < 14; ff += 4) {
      int fr = ff / 7, fc = ff % 7;
      f32x4 acc = (f32x4){0.f, 0.f, 0.f, 0.f};
#pragma unroll
      for (int kk = 0; kk < 4; kk++) {
        bf16x8 a = *(const bf16x8*)&Qs[fr * 16 + lr][kk * 32 + lke];
        bf16x8 b = *(const bf16x8*)&Ks[fc * 16 + lr][kk * 32 + lke];
        acc = __builtin_amdgcn_mfma_f32_16x16x32_bf16(a, b, acc, 0, 0, 0);
      }
#pragma unroll
      for (int j = 0; j < 4; j++)
        lg[fr * 16 + (lane >> 4) * 4 + j][fc * 16 + (lane & 15)] = acc[j] * 0.06f;
    }
    __syncthreads();
#pragma unroll
    for (int qq = 0; qq < 8; qq++) {
      int rr = wave + qq * 4;
      int i = i0 + rr;
      int c0 = lane, c1 = lane + 64;
      int e0i = i - (jlo + c0), e1i = i - (jlo + c1);
      bool v0 = (c0 < nk) && (e0i > -40) && (e0i < 40);
      bool v1 = (c1 < nk) && (e1i > -40) && (e1i < 40);
      float l0 = v0 ? lg[rr][c0] : -1e30f;
      float l1 = v1 ? lg[rr][min(c1, 111)] : -1e30f;
      float mx = fmaxf(l0, l1);
      for (int o = 32; o; o >>= 1) mx = fmaxf(mx, __shfl_xor(mx, o));
      float e0 = v0 ? __expf(l0 - mx) : 0.f;
      float e1 = v1 ? __expf(l1 - mx) : 0.f;
      float su = e0 + e1;
      for (int o = 32; o; o >>= 1) su += __shfl_xor(su, o);
      float inv = 1.f / su;
      int base = max(i - 39, 0);
      if (v0) Pa[(size_t)i * 79 + (jlo + c0) - base] = e0 * inv;
      if (v1) Pa[(size_t)i * 79 + (jlo + c1) - base] = e1 * inv;
    }
  }
}

// ---------------- fused PV, XCD-chunked + LDS-staged P + pipelined loops -----------
__global__ __launch_bounds__(256) void k_pv(const float* __restrict__ P,
                                            const float* __restrict__ Pa,
                                            const unsigned short* __restrict__ kqv,
                                            const unsigned short* __restrict__ akqv,
                                            unsigned short* __restrict__ y0b,
                                            unsigned short* __restrict__ ay0b) {
  int bid = blockIdx.x, tid = threadIdx.x;
  if (bid < 2048) {
    __shared__ float pa_s[2][80];
    int xcd = bid & 7, idx = bid >> 3;
    int half = tid >> 7, d = tid & 127;
    int i = (xcd * 256 + idx) * 2 + half;
    int jlo = max(i - 39, 0), jhi = min(i + 39, N_SEQ - 1);
    int nj = jhi - jlo + 1;                  // <= 79
    if (d < nj)
      pa_s[half][d] = Pa[(size_t)(jlo + d) * 79 + (i - max(jlo + d - 39, 0))];
    __syncthreads();
    float acc = 0.f;
#pragma unroll 8
    for (int t = 0; t < 79; t++) {
      bool v = t < nj;
      int j = v ? (jlo + t) : jhi;
      float a = v ? pa_s[half][t] : 0.f;
      acc += a * b2f(akqv[(size_t)j * 384 + 256 + d]);
    }
    ay0b[(size_t)i * 128 + d] = f2b(acc);
  } else {
    __shared__ float pv_s[40];
    int vb = bid - 2048;
    int xcd = vb & 7, idx = vb >> 3;
    int i = xcd * 512 + idx;
    int jlo = max(i - 19, 0), jhi = min(i + 19, N_SEQ - 1);
    int nj = jhi - jlo + 1;                  // <= 39
    if (tid < nj)
      pv_s[tid] = P[(size_t)(jlo + tid) * 40 + (i - max(jlo + tid - 19, 0))];
    __syncthreads();
    int d0 = tid * 4;
    float a0 = 0.f, a1 = 0.f, a2 = 0.f, a3 = 0.f;
#pragma unroll
    for (int t = 0; t < 39; t++) {
      bool v = t < nj;
      int j = v ? (jlo + t) : jhi;
      float a = v ? pv_s[t] : 0.f;
      bf16x4 vv = *(const bf16x4*)&kqv[(size_t)j * 3072 + 2048 + d0];
      a0 += a * b2f((unsigned short)vv[0]);
      a1 += a * b2f((unsigned short)vv[1]);
      a2 += a * b2f((unsigned short)vv[2]);
      a3 += a * b2f((unsigned short)vv[3]);
    }
    ushort4 o;
    o.x = f2b(a0); o.y = f2b(a1); o.z = f2b(a2); o.w = f2b(a3);
    *(ushort4*)&y0b[(size_t)i * 1024 + d0] = o;
  }
}

// ---------------- fused residual+LN pair (bf16 in) -> h_bf[4096][1152] -------------
__global__ __launch_bounds__(256) void k_ln2(const unsigned short* __restrict__ s1,
                                             const unsigned short* __restrict__ r1,
                                             const float* __restrict__ g1,
                                             const float* __restrict__ b1,
                                             const unsigned short* __restrict__ s2,
                                             const unsigned short* __restrict__ r2,
                                             const float* __restrict__ g2,
                                             const float* __restrict__ b2,
                                             unsigned short* __restrict__ dstb) {
  __shared__ float rb[8];
  int bid = blockIdx.x, tid = threadIdx.x, wave = tid >> 6, lane = tid & 63;
  if (bid < N_SEQ) {
    int i = bid;
    bf16x4 sv = *(const bf16x4*)&s1[(size_t)i * 1024 + tid * 4];
    bf16x4 rv = *(const bf16x4*)&r1[(size_t)i * 1024 + tid * 4];
    float v[4], s = 0.f, ss = 0.f;
#pragma unroll
    for (int q = 0; q < 4; q++) {
      float xx = b2f((unsigned short)sv[q]) + b2f((unsigned short)rv[q]);
      v[q] = xx; s += xx; ss += xx * xx;
    }
    for (int o = 32; o; o >>= 1) { s += __shfl_xor(s, o); ss += __shfl_xor(ss, o); }
    if (!lane) { rb[wave] = s; rb[4 + wave] = ss; }
    __syncthreads();
    float S = rb[0] + rb[1] + rb[2] + rb[3];
    float SS = rb[4] + rb[5] + rb[6] + rb[7];
    float mu = S * (1.f / 1024.f);
    float var = SS * (1.f / 1024.f) - mu * mu;
    float rstd = rsqrtf(var + 1e-6f);
    float4 gv = *(const float4*)&g1[tid * 4];
    float4 bv = *(const float4*)&b1[tid * 4];
    ushort4 o;
    o.x = f2b((v[0] - mu) * rstd * gv.x + bv.x);
    o.y = f2b((v[1] - mu) * rstd * gv.y + bv.y);
    o.z = f2b((v[2] - mu) * rstd * gv.z + bv.z);
    o.w = f2b((v[3] - mu) * rstd * gv.w + bv.w);
    *(ushort4*)&dstb[(size_t)i * H_DIM + tid * 4] = o;
  } else {
    int i = bid - N_SEQ;
    float xx = 0.f;
    if (tid < 128) xx = b2f(s2[(size_t)i * 128 + tid]) + b2f(r2[(size_t)i * 128 + tid]);
    float s = xx, ss = xx * xx;
    for (int o = 32; o; o >>= 1) { s += __shfl_xor(s, o); ss += __shfl_xor(ss, o); }
    if (!lane) { rb[wave] = s; rb[4 + wave] = ss; }
    __syncthreads();
    float S = rb[0] + rb[1] + rb[2] + rb[3];
    float SS = rb[4] + rb[5] + rb[6] + rb[7];
    float mu = S * (1.f / 128.f);
    float var = SS * (1.f / 128.f) - mu * mu;
    float rstd = rsqrtf(var + 1e-6f);
    if (tid < 128)
      dstb[(size_t)i * H_DIM + 1024 + tid] = f2b((xx - mu) * rstd * g2[tid] + b2[tid]);
  }
}

// ---------------- head: relu(h2b+b) -> LN -> dot(kd_w) -> sigmoid (bf16 in) --------
__global__ __launch_bounds__(256) void k_head(const unsigned short* __restrict__ h2b,
                                              const float* __restrict__ kab,
                                              const float* __restrict__ g,
                                              const float* __restrict__ b,
                                              const float* __restrict__ kdw,
                                              const float* __restrict__ kdb,
                                              float* __restrict__ out) {
  int i = blockIdx.x, tid = threadIdx.x, wave = tid >> 6, lane = tid & 63;
  __shared__ float rb[12];
  bf16x4 hv = *(const bf16x4*)&h2b[(size_t)i * 1024 + tid * 4];
  float4 kb = *(const float4*)&kab[tid * 4];
  float v[4], s = 0.f, ss = 0.f;
  v[0] = fmaxf(b2f((unsigned short)hv[0]) + kb.x, 0.f);
  v[1] = fmaxf(b2f((unsigned short)hv[1]) + kb.y, 0.f);
  v[2] = fmaxf(b2f((unsigned short)hv[2]) + kb.z, 0.f);
  v[3] = fmaxf(b2f((unsigned short)hv[3]) + kb.w, 0.f);
#pragma unroll
  for (int q = 0; q < 4; q++) { s += v[q]; ss += v[q] * v[q]; }
  for (int o = 32; o; o >>= 1) { s += __shfl_xor(s, o); ss += __shfl_xor(ss, o); }
  if (!lane) { rb[wave] = s; rb[4 + wave] = ss; }
  __syncthreads();
  float S = rb[0] + rb[1] + rb[2] + rb[3];
  float SS = rb[4] + rb[5] + rb[6] + rb[7];
  float mu = S * (1.f / 1024.f);
  float var = SS * (1.f / 1024.f) - mu * mu;
  float rstd = rsqrtf(var + 1e-6f);
  float4 gv = *(const float4*)&g[tid * 4];
  float4 bv = *(const float4*)&b[tid * 4];
  float4 kv = *(const float4*)&kdw[tid * 4];
  float dacc = ((v[0] - mu) * rstd * gv.x + bv.x) * kv.x +
               ((v[1] - mu) * rstd * gv.y + bv.y) * kv.y +
               ((v[2] - mu) * rstd * gv.z + bv.z) * kv.z +
               ((v[3] - mu) * rstd * gv.w + bv.w) * kv.w;
  for (int o = 32; o; o >>= 1) dacc += __shfl_xor(dacc, o);
  if (!lane) rb[8 + wave] = dacc;
  __syncthreads();
  if (tid == 0) out[i] = 1.f / (1.f + __expf(-(rb[8] + rb[9] + rb[10] + rb[11] + kdb[0])));
}

extern "C" void kernel_launch(void* const* d_in, const int* in_sizes, int n_in,
                              void* d_out, int out_size, void* d_ws, size_t ws_size,
                              hipStream_t stream) {
  const float* x      = (const float*)d_in[0];
  const float* audio  = (const float*)d_in[1];
  const float* Wk     = (const float*)d_in[2];
  const float* Wq     = (const float*)d_in[3];
  const float* Wv     = (const float*)d_in[4];
  const float* Wo     = (const float*)d_in[5];
  const float* aWk    = (const float*)d_in[6];
  const float* aWq    = (const float*)d_in[7];
  const float* aWv    = (const float*)d_in[8];
  const float* aWo    = (const float*)d_in[9];
  const float* ka_w   = (const float*)d_in[10];
  const float* ka_b   = (const float*)d_in[11];
  const float* kd_w   = (const float*)d_in[12];
  const float* kd_b   = (const float*)d_in[13];
  const float* ln_y_g = (const float*)d_in[14];
  const float* ln_y_b = (const float*)d_in[15];
  const float* ln_ka_g= (const float*)d_in[16];
  const float* ln_ka_b= (const float*)d_in[17];
  const float* ln_a_g = (const float*)d_in[18];
  const float* ln_a_b = (const float*)d_in[19];
  const float* ln_a2_g= (const float*)d_in[20];
  const float* ln_a2_b= (const float*)d_in[21];

  const size_t MB = 1024ull * 1024ull;
  if (ws_size < 90 * MB) return;

  char* w = (char*)d_ws;
  unsigned short* kqv_bf  = (unsigned short*)(w);            // [4096][3072] bf16  24MB
  unsigned short* akqv_bf = (unsigned short*)(w + 24 * MB);  // [4096][384]  bf16   3MB
  unsigned short* y1b     = (unsigned short*)(w + 27 * MB);  // [4096][1024] bf16   8MB
  unsigned short* h2b     = (unsigned short*)(w + 35 * MB);  // [4096][1024] bf16   8MB
  unsigned short* ay1b    = (unsigned short*)(w + 43 * MB);  // [4096][128]  bf16   1MB
  float* P     = (float*)(w + 44 * MB);                      // [4096][40]        640KB
  float* Pa    = (float*)(w + 45 * MB);                      // [4096][79]        1.3MB
  unsigned short* x_bf     = (unsigned short*)(w + 47 * MB); // 8MB
  unsigned short* wkqv_bf  = (unsigned short*)(w + 55 * MB); // 6MB
  unsigned short* wo_bf    = (unsigned short*)(w + 61 * MB); // 2MB
  unsigned short* kaw_bf   = (unsigned short*)(w + 63 * MB); // 2.25MB
  unsigned short* awkqv_bf = (unsigned short*)(w + 66 * MB); // 96KB
  unsigned short* awo_bf   = (unsigned short*)(w + 67 * MB); // 32KB
  unsigned short* aud_bf   = (unsigned short*)(w + 68 * MB); // 1MB
  unsigned short* y0_bf    = (unsigned short*)(w + 69 * MB); // 8MB
  unsigned short* ay0_bf   = (unsigned short*)(w + 77 * MB); // 1MB
  unsigned short* h_bf     = (unsigned short*)(w + 78 * MB); // 9MB

  float* out0 = (float*)d_out;
  float* att  = (float*)d_out + N_SEQ;

  // launch 1: convert + audio LN
  CvtArgs ca;
  const unsigned int MM4 = (M_DIM * M_DIM) / 4;
  const unsigned int AA4 = (A_DIM * A_DIM) / 4;
  ca.src[0] = x;    ca.dst[0] = x_bf;
  ca.src[1] = Wk;   ca.dst[1] = wkqv_bf;
  ca.src[2] = Wq;   ca.dst[2] = wkqv_bf + M_DIM * M_DIM;
  ca.src[3] = Wv;   ca.dst[3] = wkqv_bf + 2 * M_DIM * M_DIM;
  ca.src[4] = Wo;   ca.dst[4] = wo_bf;
  ca.src[5] = ka_w; ca.dst[5] = kaw_bf;
  ca.src[6] = aWk;  ca.dst[6] = awkqv_bf;
  ca.src[7] = aWq;  ca.dst[7] = awkqv_bf + A_DIM * A_DIM;
  ca.src[8] = aWv;  ca.dst[8] = awkqv_bf + 2 * A_DIM * A_DIM;
  ca.src[9] = aWo;  ca.dst[9] = awo_bf;
  unsigned int sz4[10] = { (N_SEQ * M_DIM) / 4, MM4, MM4, MM4, MM4,
                           (1024u * H_DIM) / 4, AA4, AA4, AA4, AA4 };
  ca.pfx[0] = 0;
  for (int i = 0; i < 10; i++) ca.pfx[i + 1] = ca.pfx[i] + sz4[i];
  ca.nblk_cvt = ca.pfx[10] / 256;
  ca.audio = audio; ca.lng = ln_a2_g; ca.lnb = ln_a2_b; ca.aud_bf = aud_bf;
  k_f2b_multi<<<ca.nblk_cvt + 2048, 256, 0, stream>>>(ca);

  // KQV + aKQV GEMMs + att zero-fill (rides the GEMM launch)
  GemmDesc dk { x_bf,   wkqv_bf,  nullptr, kqv_bf,  1024, 3072, 24, 768 };
  GemmDesc da { aud_bf, awkqv_bf, nullptr, akqv_bf, 128,  384,  3,  96  };
  k_gemmx<<<dk.nb + da.nb + 256, 256, 0, stream>>>(dk, da, att);

  // fused banded attention + fused PV (audio-first, XCD-chunked)
  k_attn<<<384, 256, 0, stream>>>(kqv_bf, akqv_bf, att, P, Pa);
  k_pv<<<2048 + N_SEQ, 256, 0, stream>>>(P, Pa, kqv_bf, akqv_bf, y0_bf, ay0_bf);

  // Wo + aWo projections -> bf16  (128x64 tiles: 512+64 blocks = 2+ blocks/CU)
  GemmDesc dw { y0_bf,  wo_bf,  nullptr, y1b,  1024, 1024, 16, 512 };
  GemmDesc dv { ay0_bf, awo_bf, nullptr, ay1b, 128,  128,  2,  64  };
  k_gemm64<<<dw.nb + dv.nb, 256, 0, stream>>>(dw, dv);

  // fused residual+LN pair (bf16 in) -> h_bf [4096][1152]
  k_ln2<<<2 * N_SEQ, 256, 0, stream>>>(y1b, x_bf, ln_y_g, ln_y_b,
                                       ay1b, aud_bf, ln_a_g, ln_a_b, h_bf);

  // MLP GEMM (K=1152) -> bf16  (128x64 tiles: 512 blocks)
  GemmDesc dm { h_bf, kaw_bf, nullptr, h2b, 1152, 1024, 16, 512 };
  GemmDesc dz { nullptr, nullptr, nullptr, nullptr, 32, 128, 1, 0 };
  k_gemm64<<<dm.nb, 256, 0, stream>>>(dm, dz);

  // relu+bias -> LN -> dot -> sigmoid
  k_head<<<N_SEQ, 256, 0, stream>>>(h2b, ka_b, ln_ka_g, ln_ka_b, kd_w, kd_b, out0);
}

// Round 11
// 160.144 us; speedup vs baseline: 1.1226x; 1.0020x over previous
//
#include <hip/hip_runtime.h>
#include <hip/hip_bf16.h>
#include <math.h>

#define N_SEQ 4096
#define M_DIM 1024
#define A_DIM 128
#define H_DIM 1152

typedef __attribute__((ext_vector_type(4))) float f32x4;
typedef __attribute__((ext_vector_type(8))) short bf16x8;
typedef __attribute__((ext_vector_type(4))) short bf16x4;

__device__ __forceinline__ unsigned short f2b(float f) {
  union { float f; unsigned int u; } v; v.f = f;
  unsigned int u = v.u;
  unsigned int r = (u + 0x7fffu + ((u >> 16) & 1u)) >> 16;
  return (unsigned short)r;
}
__device__ __forceinline__ float b2f(unsigned short u) {
  union { unsigned int i; float f; } v; v.i = ((unsigned int)u) << 16; return v.f;
}
__device__ __forceinline__ void gload_lds16(const void* g, void* l) {
  __builtin_amdgcn_global_load_lds((const __attribute__((address_space(1))) unsigned int*)g,
                                   (__attribute__((address_space(3))) unsigned int*)l,
                                   16, 0, 0);
}

// ------- launch 1: fused f32->bf16 convert (10 segs) + audio LayerNorm tail --------
struct CvtArgs {
  const float* src[10];
  unsigned short* dst[10];
  unsigned int pfx[11];
  unsigned int nblk_cvt;
  const float* audio;
  const float* lng;
  const float* lnb;
  unsigned short* aud_bf;
};
__global__ __launch_bounds__(256) void k_f2b_multi(CvtArgs a) {
  int tid = threadIdx.x;
  if (blockIdx.x >= a.nblk_cvt) {
    __shared__ float rb[8];
    int ab = blockIdx.x - a.nblk_cvt;
    int i = ab * 2 + (tid >> 7), d = tid & 127;
    float x = a.audio[(size_t)i * A_DIM + d];
    float s = x, ss = x * x;
    for (int o = 32; o; o >>= 1) { s += __shfl_xor(s, o); ss += __shfl_xor(ss, o); }
    int wave = tid >> 6, lane = tid & 63;
    if (!lane) { rb[wave] = s; rb[4 + wave] = ss; }
    __syncthreads();
    int w0 = (tid >> 7) * 2;
    float S = rb[w0] + rb[w0 + 1], SS = rb[4 + w0] + rb[4 + w0 + 1];
    float mu = S * (1.f / 128.f);
    float var = SS * (1.f / 128.f) - mu * mu;
    float rstd = rsqrtf(var + 1e-6f);
    a.aud_bf[(size_t)i * A_DIM + d] = f2b((x - mu) * rstd * a.lng[d] + a.lnb[d]);
    return;
  }
  unsigned int g = blockIdx.x * 256 + tid;
  const float* sp = a.src[0];
  unsigned short* dp = a.dst[0];
  unsigned int base = 0;
#pragma unroll
  for (int i = 1; i < 10; i++)
    if (g >= a.pfx[i]) { sp = a.src[i]; dp = a.dst[i]; base = a.pfx[i]; }
  unsigned int i4 = g - base;
  float4 f = *reinterpret_cast<const float4*>(sp + (size_t)i4 * 4);
  ushort4 o;
  o.x = f2b(f.x); o.y = f2b(f.y); o.z = f2b(f.z); o.w = f2b(f.w);
  *reinterpret_cast<ushort4*>(dp + (size_t)i4 * 4) = o;
}

// ---------------- bf16 MFMA GEMM: 128x128, 2-buffer lookahead-1 counted vmcnt ------
// LDS 32KB -> 5 blocks/CU (TLP is the mechanism at this structure, m114; deeper
// lookahead was null, R8). Tile t in buf t&1; STAGE(t+1) overlaps compute(t);
// vmcnt(4) retires exactly tile t's loads, t+1's stay in flight.
struct GemmDesc {
  const unsigned short* A;
  const unsigned short* B;
  float* Cf;
  unsigned short* Cb;
  int K, N, gx, nb;
};
__global__ __launch_bounds__(256) void k_gemmx(GemmDesc d0, GemmDesc d1, float* zf) {
  __shared__ __attribute__((aligned(16))) unsigned short As[2][128 * 32];
  __shared__ __attribute__((aligned(16))) unsigned short Bs[2][128 * 32];
  int tid = threadIdx.x;
  int bid = blockIdx.x;
  int gemmb = d0.nb + d1.nb;
  if (bid >= gemmb) {
    float4* p = (float4*)(zf + (size_t)(bid - gemmb) * 65536);
    float4 z = make_float4(0.f, 0.f, 0.f, 0.f);
#pragma unroll
    for (int k = 0; k < 64; k++) p[tid + k * 256] = z;
    return;
  }
  GemmDesc d = d0;
  int lid = bid;
  if (bid >= d0.nb) { d = d1; lid = bid - d0.nb; }
  int nwg = d.nb, q = nwg >> 3, r = nwg & 7;
  int xcd = lid & 7, idx = lid >> 3;
  int wgid = (xcd < r ? xcd * (q + 1) : r * (q + 1) + (xcd - r) * q) + idx;
  int bx = wgid % d.gx, by = wgid / d.gx;
  int row0 = by * 128, col0 = bx * 128;
  const int K = d.K, N = d.N;

  int wave = tid >> 6, lane = tid & 63;
  int wr = (wave >> 1) * 64, wc = (wave & 1) * 64;
  int lr = lane & 15;
  int lkb = ((((lane >> 4) + ((lr >> 1) & 3)) & 3)) * 16;
  int ch = wave * 2;
  int srow = ch * 16 + (lane >> 2);
  int scol = ((((lane & 3) - ((lane >> 3) & 3)) & 3)) * 8;
  const unsigned short* ga0 = d.A + (size_t)(row0 + srow) * K + scol;
  const unsigned short* ga1 = ga0 + (size_t)16 * K;
  const unsigned short* gb0 = d.B + (size_t)(col0 + srow) * K + scol;
  const unsigned short* gb1 = gb0 + (size_t)16 * K;

  f32x4 acc[4][4];
#pragma unroll
  for (int m = 0; m < 4; m++)
#pragma unroll
    for (int n = 0; n < 4; n++) acc[m][n] = (f32x4){0.f, 0.f, 0.f, 0.f};

  auto STAGE = [&](int buf, int t) {
    int k0 = t << 5;
    char* la = (char*)(&As[buf][0]) + ch * 1024;
    char* lb = (char*)(&Bs[buf][0]) + ch * 1024;
    gload_lds16(ga0 + k0, la);
    gload_lds16(ga1 + k0, la + 1024);
    gload_lds16(gb0 + k0, lb);
    gload_lds16(gb1 + k0, lb + 1024);
  };

  int nt = K >> 5;
  STAGE(0, 0);
  for (int t = 0; t < nt; t++) {
    int cur = t & 1;
    if (t + 1 < nt) {
      STAGE(cur ^ 1, t + 1);
      asm volatile("s_waitcnt vmcnt(4)" ::: "memory");   // tile t landed; t+1 in flight
    } else {
      asm volatile("s_waitcnt vmcnt(0)" ::: "memory");
    }
    __builtin_amdgcn_s_barrier();
    __builtin_amdgcn_sched_barrier(0);
    const char* pa = (const char*)(&As[cur][0]) + (wr + lr) * 64 + lkb;
    const char* pb = (const char*)(&Bs[cur][0]) + (wc + lr) * 64 + lkb;
    bf16x8 af[4], bfr[4];
#pragma unroll
    for (int m = 0; m < 4; m++) af[m] = *(const bf16x8*)(pa + m * 1024);
#pragma unroll
    for (int n = 0; n < 4; n++) bfr[n] = *(const bf16x8*)(pb + n * 1024);
#pragma unroll
    for (int m = 0; m < 4; m++)
#pragma unroll
      for (int n = 0; n < 4; n++)
        acc[m][n] = __builtin_amdgcn_mfma_f32_16x16x32_bf16(af[m], bfr[n], acc[m][n], 0, 0, 0);
    __builtin_amdgcn_sched_barrier(0);
    __builtin_amdgcn_s_barrier();                        // readers of cur done
  }
  int lq = lane >> 4;
#pragma unroll
  for (int m = 0; m < 4; m++)
#pragma unroll
    for (int n = 0; n < 4; n++)
#pragma unroll
      for (int j = 0; j < 4; j++) {
        int rr = row0 + wr + m * 16 + lq * 4 + j;
        int cc = col0 + wc + n * 16 + lr;
        if (d.Cf) d.Cf[(size_t)rr * N + cc] = acc[m][n][j];
        if (d.Cb) d.Cb[(size_t)rr * N + cc] = f2b(acc[m][n][j]);
      }
}

// ---------------- bf16 MFMA GEMM: 128x64 tile (grid-limited; keep lookahead-2) -----
__global__ __launch_bounds__(256) void k_gemm64(GemmDesc d0, GemmDesc d1) {
  __shared__ __attribute__((aligned(16))) unsigned short As[3][128 * 32];
  __shared__ __attribute__((aligned(16))) unsigned short Bs[3][64 * 32];
  int tid = threadIdx.x;
  int bid = blockIdx.x;
  GemmDesc d = d0;
  int lid = bid;
  if (bid >= d0.nb) { d = d1; lid = bid - d0.nb; }
  int nwg = d.nb, q = nwg >> 3, r = nwg & 7;
  int xcd = lid & 7, idx = lid >> 3;
  int wgid = (xcd < r ? xcd * (q + 1) : r * (q + 1) + (xcd - r) * q) + idx;
  int bx = wgid % d.gx, by = wgid / d.gx;
  int row0 = by * 128, col0 = bx * 64;
  const int K = d.K, N = d.N;

  int wave = tid >> 6, lane = tid & 63;
  int wr = (wave >> 1) * 64, wc = (wave & 1) * 32;
  int lr = lane & 15;
  int lkb = ((((lane >> 4) + ((lr >> 1) & 3)) & 3)) * 16;
  int ch = wave * 2;
  int srow = ch * 16 + (lane >> 2);
  int srB  = wave * 16 + (lane >> 2);
  int scol = ((((lane & 3) - ((lane >> 3) & 3)) & 3)) * 8;
  const unsigned short* ga0 = d.A + (size_t)(row0 + srow) * K + scol;
  const unsigned short* ga1 = ga0 + (size_t)16 * K;
  const unsigned short* gb0 = d.B + (size_t)(col0 + srB) * K + scol;

  f32x4 acc[4][2];
#pragma unroll
  for (int m = 0; m < 4; m++)
#pragma unroll
    for (int n = 0; n < 2; n++) acc[m][n] = (f32x4){0.f, 0.f, 0.f, 0.f};

  auto STAGE = [&](int buf, int t) {
    int k0 = t << 5;
    char* la = (char*)(&As[buf][0]) + ch * 1024;
    char* lb = (char*)(&Bs[buf][0]) + wave * 1024;
    gload_lds16(ga0 + k0, la);
    gload_lds16(ga1 + k0, la + 1024);
    gload_lds16(gb0 + k0, lb);
  };

  int nt = K >> 5;
  STAGE(0, 0);
  STAGE(1, 1);
  int cur = 0, sb = 2;
  for (int t = 0; t < nt; t++) {
    if (t + 2 < nt) {
      STAGE(sb, t + 2);
      asm volatile("s_waitcnt vmcnt(6)" ::: "memory");
    } else if (t + 1 < nt) {
      asm volatile("s_waitcnt vmcnt(3)" ::: "memory");
    } else {
      asm volatile("s_waitcnt vmcnt(0)" ::: "memory");
    }
    __builtin_amdgcn_s_barrier();
    __builtin_amdgcn_sched_barrier(0);
    const char* pa = (const char*)(&As[cur][0]) + (wr + lr) * 64 + lkb;
    const char* pb = (const char*)(&Bs[cur][0]) + (wc + lr) * 64 + lkb;
    bf16x8 af[4], bfr[2];
#pragma unroll
    for (int m = 0; m < 4; m++) af[m] = *(const bf16x8*)(pa + m * 1024);
#pragma unroll
    for (int n = 0; n < 2; n++) bfr[n] = *(const bf16x8*)(pb + n * 1024);
#pragma unroll
    for (int m = 0; m < 4; m++)
#pragma unroll
      for (int n = 0; n < 2; n++)
        acc[m][n] = __builtin_amdgcn_mfma_f32_16x16x32_bf16(af[m], bfr[n], acc[m][n], 0, 0, 0);
    __builtin_amdgcn_sched_barrier(0);
    __builtin_amdgcn_s_barrier();
    cur = (cur == 2) ? 0 : cur + 1;
    sb = (sb == 2) ? 0 : sb + 1;
  }
  int lq = lane >> 4;
#pragma unroll
  for (int m = 0; m < 4; m++)
#pragma unroll
    for (int n = 0; n < 2; n++)
#pragma unroll
      for (int j = 0; j < 4; j++) {
        int rr = row0 + wr + m * 16 + lq * 4 + j;
        int cc = col0 + wc + n * 16 + lr;
        if (d.Cf) d.Cf[(size_t)rr * N + cc] = acc[m][n][j];
        if (d.Cb) d.Cb[(size_t)rr * N + cc] = f2b(acc[m][n][j]);
      }
}

// ---------------- fused banded attention (video blocks 0-255, audio 256-383) --------
__global__ __launch_bounds__(256) void k_attn(const unsigned short* __restrict__ kqv,
                                              const unsigned short* __restrict__ akqv,
                                              float* __restrict__ att,
                                              float* __restrict__ P,
                                              float* __restrict__ Pa) {
  __shared__ __attribute__((aligned(16))) char smem[53504];
  int tid = threadIdx.x, wave = tid >> 6, lane = tid & 63;
  if (blockIdx.x < 256) {
    unsigned short(*Qs)[264] = (unsigned short(*)[264])smem;
    unsigned short(*Ks)[264] = (unsigned short(*)[264])(smem + 8448);
    float(*lg)[64] = (float(*)[64])(smem + 42240);
    int i0 = blockIdx.x * 16;
    int jlo = max(i0 - 19, 0);
    int jhi = min(i0 + 34, N_SEQ - 1);
    int nk = jhi - jlo + 1;                  // <= 54
    int lr = lane & 15, lke = (lane >> 4) * 8;
    f32x4 acc = (f32x4){0.f, 0.f, 0.f, 0.f};
    for (int kc = 0; kc < M_DIM; kc += 256) {
      __syncthreads();
#pragma unroll
      for (int it = 0; it < 2; it++) {
        int qq = tid + it * 256;
        int rr = qq >> 5, c = (qq & 31) * 8;
        *(bf16x8*)&Qs[rr][c] =
            *(const bf16x8*)&kqv[(size_t)(i0 + rr) * 3072 + 1024 + kc + c];
      }
#pragma unroll
      for (int it = 0; it < 8; it++) {
        int qq = tid + it * 256;
        int rr = qq >> 5, c = (qq & 31) * 8;
        bf16x8 v = {0, 0, 0, 0, 0, 0, 0, 0};
        if (rr < nk) v = *(const bf16x8*)&kqv[(size_t)(jlo + rr) * 3072 + kc + c];
        *(bf16x8*)&Ks[rr][c] = v;
      }
      __syncthreads();
#pragma unroll
      for (int kk = 0; kk < 8; kk++) {
        bf16x8 a = *(const bf16x8*)&Qs[lr][kk * 32 + lke];
        bf16x8 b = *(const bf16x8*)&Ks[wave * 16 + lr][kk * 32 + lke];
        acc = __builtin_amdgcn_mfma_f32_16x16x32_bf16(a, b, acc, 0, 0, 0);
      }
    }
#pragma unroll
    for (int j = 0; j < 4; j++)
      lg[(lane >> 4) * 4 + j][wave * 16 + (lane & 15)] = acc[j] * 0.06f;
    __syncthreads();
#pragma unroll
    for (int qq = 0; qq < 4; qq++) {
      int rr = wave + qq * 4;
      int i = i0 + rr;
      int c = lane;
      int dd = i - (jlo + c);
      bool valid = (c < nk) && (dd > -20) && (dd < 20);
      float v = valid ? lg[rr][c] : -1e30f;
      float mx = v;
      for (int o = 32; o; o >>= 1) mx = fmaxf(mx, __shfl_xor(mx, o));
      float e = valid ? __expf(v - mx) : 0.f;
      float su = e;
      for (int o = 32; o; o >>= 1) su += __shfl_xor(su, o);
      float p = e / su;
      if (valid) {
        att[(size_t)i * N_SEQ + jlo + c] = p;
        P[(size_t)i * 40 + (jlo + c) - max(i - 19, 0)] = p;
      }
    }
  } else {
    unsigned short(*Qs)[136] = (unsigned short(*)[136])smem;
    unsigned short(*Ks)[136] = (unsigned short(*)[136])(smem + 8704);
    float(*lg)[112] = (float(*)[112])(smem + 39168);
    int i0 = (blockIdx.x - 256) * 32;
    int jlo = max(i0 - 39, 0);
    int jhi = min(i0 + 70, N_SEQ - 1);
    int nk = jhi - jlo + 1;                   // <= 110
    int lr = lane & 15, lke = (lane >> 4) * 8;
#pragma unroll
    for (int it = 0; it < 2; it++) {
      int qq = tid + it * 256;
      int rr = qq >> 4, c = (qq & 15) * 8;
      *(bf16x8*)&Qs[rr][c] = *(const bf16x8*)&akqv[(size_t)(i0 + rr) * 384 + 128 + c];
    }
#pragma unroll
    for (int it = 0; it < 7; it++) {
      int qq = tid + it * 256;
      int rr = qq >> 4, c = (qq & 15) * 8;
      bf16x8 v = {0, 0, 0, 0, 0, 0, 0, 0};
      if (rr < nk) v = *(const bf16x8*)&akqv[(size_t)(jlo + rr) * 384 + c];
      *(bf16x8*)&Ks[rr][c] = v;
    }
    __syncthreads();
    for (int ff = wave; ff < 14; ff += 4) {
      int fr = ff / 7, fc = ff % 7;
      f32x4 acc = (f32x4){0.f, 0.f, 0.f, 0.f};
#pragma unroll
      for (int kk = 0; kk < 4; kk++) {
        bf16x8 a = *(const bf16x8*)&Qs[fr * 16 + lr][kk * 32 + lke];
        bf16x8 b = *(const bf16x8*)&Ks[fc * 16 + lr][kk * 32 + lke];
        acc = __builtin_amdgcn_mfma_f32_16x16x32_bf16(a, b, acc, 0, 0, 0);
      }
#pragma unroll
      for (int j = 0; j < 4; j++)
        lg[fr * 16 + (lane >> 4) * 4 + j][fc * 16 + (lane & 15)] = acc[j] * 0.06f;
    }
    __syncthreads();
#pragma unroll
    for (int qq = 0; qq < 8; qq++) {
      int rr = wave + qq * 4;
      int i = i0 + rr;
      int c0 = lane, c1 = lane + 64;
      int e0i = i - (jlo + c0), e1i = i - (jlo + c1);
      bool v0 = (c0 < nk) && (e0i > -40) && (e0i < 40);
      bool v1 = (c1 < nk) && (e1i > -40) && (e1i < 40);
      float l0 = v0 ? lg[rr][c0] : -1e30f;
      float l1 = v1 ? lg[rr][min(c1, 111)] : -1e30f;
      float mx = fmaxf(l0, l1);
      for (int o = 32; o; o >>= 1) mx = fmaxf(mx, __shfl_xor(mx, o));
      float e0 = v0 ? __expf(l0 - mx) : 0.f;
      float e1 = v1 ? __expf(l1 - mx) : 0.f;
      float su = e0 + e1;
      for (int o = 32; o; o >>= 1) su += __shfl_xor(su, o);
      float inv = 1.f / su;
      int base = max(i - 39, 0);
      if (v0) Pa[(size_t)i * 79 + (jlo + c0) - base] = e0 * inv;
      if (v1) Pa[(size_t)i * 79 + (jlo + c1) - base] = e1 * inv;
    }
  }
}

// ---------------- fused PV, XCD-chunked + LDS-staged P + pipelined loops -----------
__global__ __launch_bounds__(256) void k_pv(const float* __restrict__ P,
                                            const float* __restrict__ Pa,
                                            const unsigned short* __restrict__ kqv,
                                            const unsigned short* __restrict__ akqv,
                                            unsigned short* __restrict__ y0b,
                                            unsigned short* __restrict__ ay0b) {
  int bid = blockIdx.x, tid = threadIdx.x;
  if (bid < 2048) {
    __shared__ float pa_s[2][80];
    int xcd = bid & 7, idx = bid >> 3;
    int half = tid >> 7, d = tid & 127;
    int i = (xcd * 256 + idx) * 2 + half;
    int jlo = max(i - 39, 0), jhi = min(i + 39, N_SEQ - 1);
    int nj = jhi - jlo + 1;                  // <= 79
    if (d < nj)
      pa_s[half][d] = Pa[(size_t)(jlo + d) * 79 + (i - max(jlo + d - 39, 0))];
    __syncthreads();
    float acc = 0.f;
#pragma unroll 8
    for (int t = 0; t < 79; t++) {
      bool v = t < nj;
      int j = v ? (jlo + t) : jhi;
      float a = v ? pa_s[half][t] : 0.f;
      acc += a * b2f(akqv[(size_t)j * 384 + 256 + d]);
    }
    ay0b[(size_t)i * 128 + d] = f2b(acc);
  } else {
    __shared__ float pv_s[40];
    int vb = bid - 2048;
    int xcd = vb & 7, idx = vb >> 3;
    int i = xcd * 512 + idx;
    int jlo = max(i - 19, 0), jhi = min(i + 19, N_SEQ - 1);
    int nj = jhi - jlo + 1;                  // <= 39
    if (tid < nj)
      pv_s[tid] = P[(size_t)(jlo + tid) * 40 + (i - max(jlo + tid - 19, 0))];
    __syncthreads();
    int d0 = tid * 4;
    float a0 = 0.f, a1 = 0.f, a2 = 0.f, a3 = 0.f;
#pragma unroll
    for (int t = 0; t < 39; t++) {
      bool v = t < nj;
      int j = v ? (jlo + t) : jhi;
      float a = v ? pv_s[t] : 0.f;
      bf16x4 vv = *(const bf16x4*)&kqv[(size_t)j * 3072 + 2048 + d0];
      a0 += a * b2f((unsigned short)vv[0]);
      a1 += a * b2f((unsigned short)vv[1]);
      a2 += a * b2f((unsigned short)vv[2]);
      a3 += a * b2f((unsigned short)vv[3]);
    }
    ushort4 o;
    o.x = f2b(a0); o.y = f2b(a1); o.z = f2b(a2); o.w = f2b(a3);
    *(ushort4*)&y0b[(size_t)i * 1024 + d0] = o;
  }
}

// ---------------- fused residual+LN pair (bf16 in) -> h_bf[4096][1152] -------------
__global__ __launch_bounds__(256) void k_ln2(const unsigned short* __restrict__ s1,
                                             const unsigned short* __restrict__ r1,
                                             const float* __restrict__ g1,
                                             const float* __restrict__ b1,
                                             const unsigned short* __restrict__ s2,
                                             const unsigned short* __restrict__ r2,
                                             const float* __restrict__ g2,
                                             const float* __restrict__ b2,
                                             unsigned short* __restrict__ dstb) {
  __shared__ float rb[8];
  int bid = blockIdx.x, tid = threadIdx.x, wave = tid >> 6, lane = tid & 63;
  if (bid < N_SEQ) {
    int i = bid;
    bf16x4 sv = *(const bf16x4*)&s1[(size_t)i * 1024 + tid * 4];
    bf16x4 rv = *(const bf16x4*)&r1[(size_t)i * 1024 + tid * 4];
    float v[4], s = 0.f, ss = 0.f;
#pragma unroll
    for (int q = 0; q < 4; q++) {
      float xx = b2f((unsigned short)sv[q]) + b2f((unsigned short)rv[q]);
      v[q] = xx; s += xx; ss += xx * xx;
    }
    for (int o = 32; o; o >>= 1) { s += __shfl_xor(s, o); ss += __shfl_xor(ss, o); }
    if (!lane) { rb[wave] = s; rb[4 + wave] = ss; }
    __syncthreads();
    float S = rb[0] + rb[1] + rb[2] + rb[3];
    float SS = rb[4] + rb[5] + rb[6] + rb[7];
    float mu = S * (1.f / 1024.f);
    float var = SS * (1.f / 1024.f) - mu * mu;
    float rstd = rsqrtf(var + 1e-6f);
    float4 gv = *(const float4*)&g1[tid * 4];
    float4 bv = *(const float4*)&b1[tid * 4];
    ushort4 o;
    o.x = f2b((v[0] - mu) * rstd * gv.x + bv.x);
    o.y = f2b((v[1] - mu) * rstd * gv.y + bv.y);
    o.z = f2b((v[2] - mu) * rstd * gv.z + bv.z);
    o.w = f2b((v[3] - mu) * rstd * gv.w + bv.w);
    *(ushort4*)&dstb[(size_t)i * H_DIM + tid * 4] = o;
  } else {
    int i = bid - N_SEQ;
    float xx = 0.f;
    if (tid < 128) xx = b2f(s2[(size_t)i * 128 + tid]) + b2f(r2[(size_t)i * 128 + tid]);
    float s = xx, ss = xx * xx;
    for (int o = 32; o; o >>= 1) { s += __shfl_xor(s, o); ss += __shfl_xor(ss, o); }
    if (!lane) { rb[wave] = s; rb[4 + wave] = ss; }
    __syncthreads();
    float S = rb[0] + rb[1] + rb[2] + rb[3];
    float SS = rb[4] + rb[5] + rb[6] + rb[7];
    float mu = S * (1.f / 128.f);
    float var = SS * (1.f / 128.f) - mu * mu;
    float rstd = rsqrtf(var + 1e-6f);
    if (tid < 128)
      dstb[(size_t)i * H_DIM + 1024 + tid] = f2b((xx - mu) * rstd * g2[tid] + b2[tid]);
  }
}

// ---------------- head: relu(h2b+b) -> LN -> dot(kd_w) -> sigmoid (bf16 in) --------
__global__ __launch_bounds__(256) void k_head(const unsigned short* __restrict__ h2b,
                                              const float* __restrict__ kab,
                                              const float* __restrict__ g,
                                              const float* __restrict__ b,
                                              const float* __restrict__ kdw,
                                              const float* __restrict__ kdb,
                                              float* __restrict__ out) {
  int i = blockIdx.x, tid = threadIdx.x, wave = tid >> 6, lane = tid & 63;
  __shared__ float rb[12];
  bf16x4 hv = *(const bf16x4*)&h2b[(size_t)i * 1024 + tid * 4];
  float4 kb = *(const float4*)&kab[tid * 4];
  float v[4], s = 0.f, ss = 0.f;
  v[0] = fmaxf(b2f((unsigned short)hv[0]) + kb.x, 0.f);
  v[1] = fmaxf(b2f((unsigned short)hv[1]) + kb.y, 0.f);
  v[2] = fmaxf(b2f((unsigned short)hv[2]) + kb.z, 0.f);
  v[3] = fmaxf(b2f((unsigned short)hv[3]) + kb.w, 0.f);
#pragma unroll
  for (int q = 0; q < 4; q++) { s += v[q]; ss += v[q] * v[q]; }
  for (int o = 32; o; o >>= 1) { s += __shfl_xor(s, o); ss += __shfl_xor(ss, o); }
  if (!lane) { rb[wave] = s; rb[4 + wave] = ss; }
  __syncthreads();
  float S = rb[0] + rb[1] + rb[2] + rb[3];
  float SS = rb[4] + rb[5] + rb[6] + rb[7];
  float mu = S * (1.f / 1024.f);
  float var = SS * (1.f / 1024.f) - mu * mu;
  float rstd = rsqrtf(var + 1e-6f);
  float4 gv = *(const float4*)&g[tid * 4];
  float4 bv = *(const float4*)&b[tid * 4];
  float4 kv = *(const float4*)&kdw[tid * 4];
  float dacc = ((v[0] - mu) * rstd * gv.x + bv.x) * kv.x +
               ((v[1] - mu) * rstd * gv.y + bv.y) * kv.y +
               ((v[2] - mu) * rstd * gv.z + bv.z) * kv.z +
               ((v[3] - mu) * rstd * gv.w + bv.w) * kv.w;
  for (int o = 32; o; o >>= 1) dacc += __shfl_xor(dacc, o);
  if (!lane) rb[8 + wave] = dacc;
  __syncthreads();
  if (tid == 0) out[i] = 1.f / (1.f + __expf(-(rb[8] + rb[9] + rb[10] + rb[11] + kdb[0])));
}

extern "C" void kernel_launch(void* const* d_in, const int* in_sizes, int n_in,
                              void* d_out, int out_size, void* d_ws, size_t ws_size,
                              hipStream_t stream) {
  const float* x      = (const float*)d_in[0];
  const float* audio  = (const float*)d_in[1];
  const float* Wk     = (const float*)d_in[2];
  const float* Wq     = (const float*)d_in[3];
  const float* Wv     = (const float*)d_in[4];
  const float* Wo     = (const float*)d_in[5];
  const float* aWk    = (const float*)d_in[6];
  const float* aWq    = (const float*)d_in[7];
  const float* aWv    = (const float*)d_in[8];
  const float* aWo    = (const float*)d_in[9];
  const float* ka_w   = (const float*)d_in[10];
  const float* ka_b   = (const float*)d_in[11];
  const float* kd_w   = (const float*)d_in[12];
  const float* kd_b   = (const float*)d_in[13];
  const float* ln_y_g = (const float*)d_in[14];
  const float* ln_y_b = (const float*)d_in[15];
  const float* ln_ka_g= (const float*)d_in[16];
  const float* ln_ka_b= (const float*)d_in[17];
  const float* ln_a_g = (const float*)d_in[18];
  const float* ln_a_b = (const float*)d_in[19];
  const float* ln_a2_g= (const float*)d_in[20];
  const float* ln_a2_b= (const float*)d_in[21];

  const size_t MB = 1024ull * 1024ull;
  if (ws_size < 90 * MB) return;

  char* w = (char*)d_ws;
  unsigned short* kqv_bf  = (unsigned short*)(w);            // [4096][3072] bf16  24MB
  unsigned short* akqv_bf = (unsigned short*)(w + 24 * MB);  // [4096][384]  bf16   3MB
  unsigned short* y1b     = (unsigned short*)(w + 27 * MB);  // [4096][1024] bf16   8MB
  unsigned short* h2b     = (unsigned short*)(w + 35 * MB);  // [4096][1024] bf16   8MB
  unsigned short* ay1b    = (unsigned short*)(w + 43 * MB);  // [4096][128]  bf16   1MB
  float* P     = (float*)(w + 44 * MB);                      // [4096][40]        640KB
  float* Pa    = (float*)(w + 45 * MB);                      // [4096][79]        1.3MB
  unsigned short* x_bf     = (unsigned short*)(w + 47 * MB); // 8MB
  unsigned short* wkqv_bf  = (unsigned short*)(w + 55 * MB); // 6MB
  unsigned short* wo_bf    = (unsigned short*)(w + 61 * MB); // 2MB
  unsigned short* kaw_bf   = (unsigned short*)(w + 63 * MB); // 2.25MB
  unsigned short* awkqv_bf = (unsigned short*)(w + 66 * MB); // 96KB
  unsigned short* awo_bf   = (unsigned short*)(w + 67 * MB); // 32KB
  unsigned short* aud_bf   = (unsigned short*)(w + 68 * MB); // 1MB
  unsigned short* y0_bf    = (unsigned short*)(w + 69 * MB); // 8MB
  unsigned short* ay0_bf   = (unsigned short*)(w + 77 * MB); // 1MB
  unsigned short* h_bf     = (unsigned short*)(w + 78 * MB); // 9MB

  float* out0 = (float*)d_out;
  float* att  = (float*)d_out + N_SEQ;

  // launch 1: convert + audio LN
  CvtArgs ca;
  const unsigned int MM4 = (M_DIM * M_DIM) / 4;
  const unsigned int AA4 = (A_DIM * A_DIM) / 4;
  ca.src[0] = x;    ca.dst[0] = x_bf;
  ca.src[1] = Wk;   ca.dst[1] = wkqv_bf;
  ca.src[2] = Wq;   ca.dst[2] = wkqv_bf + M_DIM * M_DIM;
  ca.src[3] = Wv;   ca.dst[3] = wkqv_bf + 2 * M_DIM * M_DIM;
  ca.src[4] = Wo;   ca.dst[4] = wo_bf;
  ca.src[5] = ka_w; ca.dst[5] = kaw_bf;
  ca.src[6] = aWk;  ca.dst[6] = awkqv_bf;
  ca.src[7] = aWq;  ca.dst[7] = awkqv_bf + A_DIM * A_DIM;
  ca.src[8] = aWv;  ca.dst[8] = awkqv_bf + 2 * A_DIM * A_DIM;
  ca.src[9] = aWo;  ca.dst[9] = awo_bf;
  unsigned int sz4[10] = { (N_SEQ * M_DIM) / 4, MM4, MM4, MM4, MM4,
                           (1024u * H_DIM) / 4, AA4, AA4, AA4, AA4 };
  ca.pfx[0] = 0;
  for (int i = 0; i < 10; i++) ca.pfx[i + 1] = ca.pfx[i] + sz4[i];
  ca.nblk_cvt = ca.pfx[10] / 256;
  ca.audio = audio; ca.lng = ln_a2_g; ca.lnb = ln_a2_b; ca.aud_bf = aud_bf;
  k_f2b_multi<<<ca.nblk_cvt + 2048, 256, 0, stream>>>(ca);

  // KQV + aKQV GEMMs + att zero-fill (rides the GEMM launch)
  GemmDesc dk { x_bf,   wkqv_bf,  nullptr, kqv_bf,  1024, 3072, 24, 768 };
  GemmDesc da { aud_bf, awkqv_bf, nullptr, akqv_bf, 128,  384,  3,  96  };
  k_gemmx<<<dk.nb + da.nb + 256, 256, 0, stream>>>(dk, da, att);

  // fused banded attention + fused PV (audio-first, XCD-chunked)
  k_attn<<<384, 256, 0, stream>>>(kqv_bf, akqv_bf, att, P, Pa);
  k_pv<<<2048 + N_SEQ, 256, 0, stream>>>(P, Pa, kqv_bf, akqv_bf, y0_bf, ay0_bf);

  // Wo + aWo projections -> bf16  (128x64 tiles)
  GemmDesc dw { y0_bf,  wo_bf,  nullptr, y1b,  1024, 1024, 16, 512 };
  GemmDesc dv { ay0_bf, awo_bf, nullptr, ay1b, 128,  128,  2,  64  };
  k_gemm64<<<dw.nb + dv.nb, 256, 0, stream>>>(dw, dv);

  // fused residual+LN pair (bf16 in) -> h_bf [4096][1152]
  k_ln2<<<2 * N_SEQ, 256, 0, stream>>>(y1b, x_bf, ln_y_g, ln_y_b,
                                       ay1b, aud_bf, ln_a_g, ln_a_b, h_bf);

  // MLP GEMM (K=1152) -> bf16  (128x64 tiles)
  GemmDesc dm { h_bf, kaw_bf, nullptr, h2b, 1152, 1024, 16, 512 };
  GemmDesc dz { nullptr, nullptr, nullptr, nullptr, 32, 128, 1, 0 };
  k_gemm64<<<dm.nb, 256, 0, stream>>>(dm, dz);

  // relu+bias -> LN -> dot -> sigmoid
  k_head<<<N_SEQ, 256, 0, stream>>>(h2b, ka_b, ln_ka_g, ln_ka_b, kd_w, kd_b, out0);
}